// Round 6
// baseline (527.234 us; speedup 1.0000x reference)
//
#include <hip/hip_runtime.h>
#include <hip/hip_bf16.h>
#include <math.h>
#include <stdint.h>

// ---------------------------------------------------------------------------
// VectorTokenizer: x ->(enc MLP)-> z -> categorical(threefry key(1)) tokens
//   -> z_q = sum of codebook rows -> (dec MLP) -> rec
// Outputs concatenated: z (4096*16384) | z_q (4096*256) | rec (4096*512), f32
//
// R6: fusion v2. Keep R4's proven 128x128 / 256-thread / 16KB-LDS MFMA GEMM
// (the ~2.6 blocks/CU co-residency is what makes epilogue VALU overlap
// another block's MFMA). Epilogue computes fast-gumbel top-2 PARTIALS per
// (row, 64-col half) -> ws (no extra barriers); tiny merge kernel finishes
// tokens/s1v/amb. h->bf16 fused into enc1. Exact refine unchanged.
// ---------------------------------------------------------------------------

#define BATCH 4096
#define KTOK  32
#define VOCAB 512
#define DMODEL 512
#define ZDIM  16384
#define EDIM  256
#define MARGIN 0.03125f

typedef __attribute__((ext_vector_type(8))) short short8v;
typedef __attribute__((ext_vector_type(4))) float f32x4;

// ----------------------- threefry2x32 (JAX-compatible) ---------------------
__device__ __forceinline__ void threefry2x32(uint32_t k0, uint32_t k1,
                                             uint32_t x0, uint32_t x1,
                                             uint32_t& y0, uint32_t& y1) {
    uint32_t ks0 = k0, ks1 = k1, ks2 = k0 ^ k1 ^ 0x1BD11BDAu;
    x0 += ks0; x1 += ks1;
#define TFR(r) { x0 += x1; x1 = __builtin_rotateleft32(x1, r); x1 ^= x0; }
    TFR(13) TFR(15) TFR(26) TFR(6)
    x0 += ks1; x1 += ks2 + 1u;
    TFR(17) TFR(29) TFR(16) TFR(24)
    x0 += ks2; x1 += ks0 + 2u;
    TFR(13) TFR(15) TFR(26) TFR(6)
    x0 += ks0; x1 += ks1 + 3u;
    TFR(17) TFR(29) TFR(16) TFR(24)
    x0 += ks1; x1 += ks2 + 4u;
    TFR(13) TFR(15) TFR(26) TFR(6)
    x0 += ks2; x1 += ks0 + 5u;
#undef TFR
    y0 = x0; y1 = x1;
}

// exact path (refine): matches JAX bit-for-bit
__device__ __forceinline__ float jax_gumbel(uint64_t e) {
    const float TINY = 1.17549435e-38f;
    uint32_t y0, y1;
    threefry2x32(0u, 1u, (uint32_t)(e >> 32), (uint32_t)(e & 0xffffffffull), y0, y1);
    uint32_t bits = y0 ^ y1;
    float u = __uint_as_float(0x3f800000u | (bits >> 9)) - 1.0f;
    u = u * 1.0f + TINY;
    u = fmaxf(TINY, u);
    return -logf(-logf(u));
}

// fast path (filter only): |g_fast - g_exact| <~ 1e-4 << MARGIN
__device__ __forceinline__ float fast_gumbel(uint32_t e32) {
    const float TINY = 1.17549435e-38f;
    const float LN2 = 0.69314718056f;
    uint32_t y0, y1;
    threefry2x32(0u, 1u, 0u, e32, y0, y1);
    uint32_t bits = y0 ^ y1;
    float f = __uint_as_float(0x3f800000u | (bits >> 9));  // [1,2)
    float u = f - 1.0f;          // exact (Sterbenz)
    float d = 2.0f - f;          // exact = 1-u
    u = fmaxf(u, TINY);
    float e_hw = -LN2 * __builtin_amdgcn_logf(u);
    float e_poly = d * fmaf(d, fmaf(d, 0.33333333f, 0.5f), 1.0f);
    float e = (d < 0.002f) ? e_poly : e_hw;
    return -LN2 * __builtin_amdgcn_logf(e);
}

__device__ __forceinline__ unsigned short f32_to_bf16_rne(float f) {
    uint32_t u = __float_as_uint(f);
    uint32_t r = (u + 0x7fffu + ((u >> 16) & 1u)) >> 16;
    return (unsigned short)r;
}

// top-2 helpers (tie -> lower index wins, matching jnp.argmax)
__device__ __forceinline__ void top2_push(float& s1, float& s2, int& v1,
                                          float s, int v) {
    if (s > s1 || (s == s1 && v < v1)) { s2 = s1; s1 = s; v1 = v; }
    else s2 = fmaxf(s2, s);
}
__device__ __forceinline__ void top2_merge(float& s1, float& s2, int& v1,
                                           float os1, float os2, int ov1) {
    if (os1 > s1 || (os1 == s1 && ov1 < v1)) {
        s2 = fmaxf(s1, os2);
        s1 = os1; v1 = ov1;
    } else {
        s2 = fmaxf(s2, os1);
    }
}

__device__ __forceinline__ void gload16(const unsigned short* src,
                                        unsigned short* lds_base) {
    __builtin_amdgcn_global_load_lds(
        (const __attribute__((address_space(1))) unsigned int*)src,
        (__attribute__((address_space(3))) unsigned int*)lds_base, 16, 0, 0);
}

// ------------------ tiled f32 GEMM, 64x64 (small layers) -------------------
// k-ascending single fmaf chain per output => bit-exact vs np.
// Optionally also writes bf16 copy of C (enc1 -> hb).
template<bool RELU>
__global__ __launch_bounds__(256)
void gemm_f32_64(const float* __restrict__ A, const float* __restrict__ B,
                 const float* __restrict__ bias, float* __restrict__ C,
                 unsigned short* __restrict__ Cb,
                 int M, int N, int K) {
    constexpr int BK = 16;
    __shared__ __align__(16) float As[BK][68];
    __shared__ __align__(16) float Bs[BK][68];

    const int tid = threadIdx.x;
    const int tx = tid % 16;
    const int ty = tid / 16;
    const int brow = blockIdx.y * 64;
    const int bcol = blockIdx.x * 64;

    float acc[4][4] = {};

    for (int k0 = 0; k0 < K; k0 += BK) {
        {
            int r = tid >> 2, c4 = tid & 3;
            float4 v = *(const float4*)&A[(size_t)(brow + r) * K + k0 + c4 * 4];
            As[c4 * 4 + 0][r] = v.x;
            As[c4 * 4 + 1][r] = v.y;
            As[c4 * 4 + 2][r] = v.z;
            As[c4 * 4 + 3][r] = v.w;
        }
        {
            int r = tid >> 4, c4 = tid & 15;
            *(float4*)&Bs[r][c4 * 4] = *(const float4*)&B[(size_t)(k0 + r) * N + bcol + c4 * 4];
        }
        __syncthreads();

#pragma unroll
        for (int kk = 0; kk < BK; ++kk) {
            float a[4], b[4];
            *(float4*)&a[0] = *(const float4*)&As[kk][ty * 4];
            *(float4*)&b[0] = *(const float4*)&Bs[kk][tx * 4];
#pragma unroll
            for (int i = 0; i < 4; ++i)
#pragma unroll
                for (int j = 0; j < 4; ++j)
                    acc[i][j] = fmaf(a[i], b[j], acc[i][j]);
        }
        __syncthreads();
    }

#pragma unroll
    for (int i = 0; i < 4; ++i) {
        int row = brow + ty * 4 + i;
        int col = bcol + tx * 4;
        float4 v;
        v.x = acc[i][0] + bias[col + 0];
        v.y = acc[i][1] + bias[col + 1];
        v.z = acc[i][2] + bias[col + 2];
        v.w = acc[i][3] + bias[col + 3];
        if (RELU) {
            v.x = fmaxf(v.x, 0.0f); v.y = fmaxf(v.y, 0.0f);
            v.z = fmaxf(v.z, 0.0f); v.w = fmaxf(v.w, 0.0f);
        }
        *(float4*)&C[(size_t)row * N + col] = v;
        if (Cb) {
            ushort4 o;
            o.x = f32_to_bf16_rne(v.x);
            o.y = f32_to_bf16_rne(v.y);
            o.z = f32_to_bf16_rne(v.z);
            o.w = f32_to_bf16_rne(v.w);
            *(ushort4*)&Cb[(size_t)row * N + col] = o;
        }
    }
}

// ---------------- tiled f32 GEMM, 128x128 (fallback big) -------------------
template<bool RELU>
__global__ __launch_bounds__(256)
void gemm_f32(const float* __restrict__ A, const float* __restrict__ B,
              const float* __restrict__ bias, float* __restrict__ C,
              int M, int N, int K) {
    constexpr int BM = 128, BN = 128, BK = 16, TM = 8, TN = 8;
    __shared__ __align__(16) float As[BK][BM + 4];
    __shared__ __align__(16) float Bs[BK][BN + 4];

    const int tid = threadIdx.x;
    const int tx = tid % (BN / TN);
    const int ty = tid / (BN / TN);
    const int brow = blockIdx.y * BM;
    const int bcol = blockIdx.x * BN;

    float acc[TM][TN] = {};

    for (int k0 = 0; k0 < K; k0 += BK) {
#pragma unroll
        for (int f = tid; f < BM * BK / 4; f += 256) {
            int r = f / (BK / 4);
            int c4 = f % (BK / 4);
            float4 v = *(const float4*)&A[(size_t)(brow + r) * K + k0 + c4 * 4];
            As[c4 * 4 + 0][r] = v.x;
            As[c4 * 4 + 1][r] = v.y;
            As[c4 * 4 + 2][r] = v.z;
            As[c4 * 4 + 3][r] = v.w;
        }
#pragma unroll
        for (int f = tid; f < BK * BN / 4; f += 256) {
            int r = f / (BN / 4);
            int c4 = f % (BN / 4);
            *(float4*)&Bs[r][c4 * 4] = *(const float4*)&B[(size_t)(k0 + r) * N + bcol + c4 * 4];
        }
        __syncthreads();

#pragma unroll
        for (int kk = 0; kk < BK; ++kk) {
            float a[TM], b[TN];
            *(float4*)&a[0] = *(const float4*)&As[kk][ty * TM];
            *(float4*)&a[4] = *(const float4*)&As[kk][ty * TM + 4];
            *(float4*)&b[0] = *(const float4*)&Bs[kk][tx * TN];
            *(float4*)&b[4] = *(const float4*)&Bs[kk][tx * TN + 4];
#pragma unroll
            for (int i = 0; i < TM; ++i)
#pragma unroll
                for (int j = 0; j < TN; ++j)
                    acc[i][j] = fmaf(a[i], b[j], acc[i][j]);
        }
        __syncthreads();
    }

#pragma unroll
    for (int i = 0; i < TM; ++i) {
        int row = brow + ty * TM + i;
#pragma unroll
        for (int j = 0; j < TN; j += 4) {
            int col = bcol + tx * TN + j;
            float4 v;
            v.x = acc[i][j + 0] + bias[col + 0];
            v.y = acc[i][j + 1] + bias[col + 1];
            v.z = acc[i][j + 2] + bias[col + 2];
            v.w = acc[i][j + 3] + bias[col + 3];
            if (RELU) {
                v.x = fmaxf(v.x, 0.0f); v.y = fmaxf(v.y, 0.0f);
                v.z = fmaxf(v.z, 0.0f); v.w = fmaxf(v.w, 0.0f);
            }
            *(float4*)&C[(size_t)row * N + col] = v;
        }
    }
}

// ---- f32 [R][C] -> bf16 [C][R] transpose, optionally also f32 [C][R] ------
__global__ __launch_bounds__(256)
void transpose_w2(const float* __restrict__ src, unsigned short* __restrict__ dstb,
                  float* __restrict__ dstf, int R, int C, int writeF) {
    __shared__ float tile[32][33];
    const int c0 = blockIdx.x * 32, r0 = blockIdx.y * 32;
    const int tx = threadIdx.x % 32, ty = threadIdx.x / 32;
#pragma unroll
    for (int i = ty; i < 32; i += 8)
        tile[i][tx] = src[(size_t)(r0 + i) * C + c0 + tx];
    __syncthreads();
#pragma unroll
    for (int i = ty; i < 32; i += 8) {
        float v = tile[tx][i];
        size_t o = (size_t)(c0 + i) * R + r0 + tx;
        dstb[o] = f32_to_bf16_rne(v);
        if (writeF) dstf[o] = v;
    }
}

// --------- bf16 MFMA GEMM (R4 structure) + fused gumbel partials -----------
// 128x128 tile, BK=32, 4 waves (2x2), wave 64x64 via 4x4 16x16x32 frags.
// Epilogue per m-slice: z write + fast-gumbel top-2 over this wave's 64-col
// half, butterfly over 16 l15-lanes, l15==0 writes partial (s1,s2,v) to ws.
__global__ __launch_bounds__(256)
void gemm_mfma_fused(const unsigned short* __restrict__ A,
                     const unsigned short* __restrict__ Bt,
                     const float* __restrict__ bias,
                     float* __restrict__ C,
                     float4* __restrict__ part,
                     int M, int N, int K) {
    constexpr int BM = 128, BN = 128, BK = 32;
    __shared__ unsigned short As[BM * BK];
    __shared__ unsigned short Bs[BN * BK];

    const int nwg = gridDim.x * gridDim.y;
    const int lid = blockIdx.y * gridDim.x + blockIdx.x;
    const int cpx = nwg >> 3;
    const int swz = (lid & 7) * cpx + (lid >> 3);
    const int bx = swz % gridDim.x;
    const int by = swz / gridDim.x;

    const int tid = threadIdx.x;
    const int wid = tid >> 6;
    const int lane = tid & 63;
    const int wr = wid >> 1, wc = wid & 1;
    const int l15 = lane & 15, lq = lane >> 4;
    const int brow = by * BM;
    const int bcol = bx * BN;

    const int g1 = tid;
    const int g2 = tid + 256;
    const size_t a1 = (size_t)(brow + (g1 >> 2)) * K + (g1 & 3) * 8;
    const size_t a2 = (size_t)(brow + (g2 >> 2)) * K + (g2 & 3) * 8;
    const size_t b1 = (size_t)(bcol + (g1 >> 2)) * K + (g1 & 3) * 8;
    const size_t b2 = (size_t)(bcol + (g2 >> 2)) * K + (g2 & 3) * 8;
    unsigned short* as_base1 = As + (size_t)wid * 64 * 8;
    unsigned short* as_base2 = As + (size_t)(256 + wid * 64) * 8;
    unsigned short* bs_base1 = Bs + (size_t)wid * 64 * 8;
    unsigned short* bs_base2 = Bs + (size_t)(256 + wid * 64) * 8;

    f32x4 acc[4][4];
#pragma unroll
    for (int m = 0; m < 4; ++m)
#pragma unroll
        for (int n = 0; n < 4; ++n) acc[m][n] = (f32x4){0.f, 0.f, 0.f, 0.f};

    for (int k0 = 0; k0 < K; k0 += BK) {
        gload16(A + a1 + k0, as_base1);
        gload16(A + a2 + k0, as_base2);
        gload16(Bt + b1 + k0, bs_base1);
        gload16(Bt + b2 + k0, bs_base2);
        __syncthreads();

        short8v af[4], bf[4];
#pragma unroll
        for (int m = 0; m < 4; ++m)
            af[m] = *(const short8v*)&As[(wr * 64 + m * 16 + l15) * BK + lq * 8];
#pragma unroll
        for (int n = 0; n < 4; ++n)
            bf[n] = *(const short8v*)&Bs[(wc * 64 + n * 16 + l15) * BK + lq * 8];
#pragma unroll
        for (int m = 0; m < 4; ++m)
#pragma unroll
            for (int n = 0; n < 4; ++n)
                acc[m][n] = __builtin_amdgcn_mfma_f32_16x16x32_bf16(
                    af[m], bf[n], acc[m][n], 0, 0, 0);
        __syncthreads();
    }

    // ---- epilogue: z write + fused top-2 partials (no barriers) ----
    const int kb = bcol >> 9;                     // token block 0..31
    const int hx = ((bcol & 511) >> 6) + wc;      // 64-col half index 0..7

#pragma unroll
    for (int m = 0; m < 4; ++m) {
        float s1[4], s2[4];
        int v1[4];
#pragma unroll
        for (int r = 0; r < 4; ++r) {
            s1[r] = -INFINITY; s2[r] = -INFINITY; v1[r] = VOCAB;
        }
#pragma unroll
        for (int n = 0; n < 4; ++n) {
            const int col = bcol + wc * 64 + n * 16 + l15;
            const int vglob = col & 511;          // vocab index
            const float bv = bias[col];
#pragma unroll
            for (int r = 0; r < 4; ++r) {
                const int row = brow + wr * 64 + m * 16 + lq * 4 + r;
                const float val = acc[m][n][r] + bv;
                C[(size_t)row * N + col] = val;
                const uint32_t t = (uint32_t)row * KTOK + kb;
                const float g = fast_gumbel(t * (uint32_t)VOCAB + (uint32_t)vglob);
                top2_push(s1[r], s2[r], v1[r], val + g, vglob);
            }
        }
        // butterfly across the 16 l15 lanes (same lq -> same rows)
#pragma unroll
        for (int off = 1; off < 16; off <<= 1) {
#pragma unroll
            for (int r = 0; r < 4; ++r) {
                float os1 = __shfl_xor(s1[r], off);
                float os2 = __shfl_xor(s2[r], off);
                int   ov1 = __shfl_xor(v1[r], off);
                top2_merge(s1[r], s2[r], v1[r], os1, os2, ov1);
            }
        }
        if (l15 == 0) {
#pragma unroll
            for (int r = 0; r < 4; ++r) {
                const int row = brow + wr * 64 + m * 16 + lq * 4 + r;
                const uint32_t t = (uint32_t)row * KTOK + kb;
                float4 p;
                p.x = s1[r]; p.y = s2[r];
                p.z = __int_as_float(v1[r]); p.w = 0.f;
                part[(size_t)t * 8 + hx] = p;
            }
        }
    }
}

// -------- merge partials -> tokens/s1v/amb (1 thread / token) --------------
__global__ __launch_bounds__(256)
void merge_sample(const float4* __restrict__ part, int* __restrict__ tokens,
                  float* __restrict__ s1v, int* __restrict__ amb,
                  int* __restrict__ ambCount) {
    const int t = blockIdx.x * 256 + threadIdx.x;   // token 0..131071
    const int lane = threadIdx.x & 63;
    float S1 = -INFINITY, S2 = -INFINITY;
    int V1 = VOCAB;
#pragma unroll
    for (int hx = 0; hx < 8; ++hx) {
        float4 p = part[(size_t)t * 8 + hx];
        top2_merge(S1, S2, V1, p.x, p.y, __float_as_int(p.z));
    }
    tokens[t] = V1;
    s1v[t] = S1;
    const bool pred = (S1 - S2 < MARGIN);
    unsigned long long mask = __ballot(pred);
    if (pred) {
        const int leader = (int)__ffsll((long long)mask) - 1;
        int base = 0;
        if (lane == leader) base = atomicAdd(ambCount, __popcll(mask));
        base = __shfl(base, leader);
        const int slot = base + __popcll(mask & ((1ull << lane) - 1ull));
        amb[slot] = t;
    }
}

// ------ refine: w2t f32 rows, ballot-compacted candidates ------------------
__global__ __launch_bounds__(64)
void refine_tokens2(const float* __restrict__ z, const float* __restrict__ h,
                    const float* __restrict__ w2t, const float* __restrict__ eb2,
                    const int* __restrict__ amb, const int* __restrict__ ambCount,
                    const float* __restrict__ s1v, int* __restrict__ tok) {
    __shared__ float hrow[DMODEL];
    __shared__ int candv[64];
    const int cnt = *ambCount;
    const int lane = threadIdx.x;

    for (int i = blockIdx.x; i < cnt; i += gridDim.x) {
        const int t = amb[i];
        const int b = t >> 5;
        const int kb = t & 31;
        const float* zr = z + (size_t)t * VOCAB;
        const float s1 = s1v[t];

        {
            float4 hv0 = *(const float4*)&h[(size_t)b * DMODEL + lane * 8];
            float4 hv1 = *(const float4*)&h[(size_t)b * DMODEL + lane * 8 + 4];
            *(float4*)&hrow[lane * 8] = hv0;
            *(float4*)&hrow[lane * 8 + 4] = hv1;
        }

        int base = 0;
#pragma unroll
        for (int half = 0; half < 2; ++half) {
            int e0 = half * 256 + lane * 4;
            float4 zv = *(const float4*)&zr[e0];
            float zs[4] = {zv.x, zv.y, zv.z, zv.w};
#pragma unroll
            for (int j = 0; j < 4; ++j) {
                int v = e0 + j;
                float s = zs[j] + fast_gumbel((uint32_t)t * VOCAB + v);
                bool pred = (s >= s1 - MARGIN);
                unsigned long long mask = __ballot(pred);
                if (pred) {
                    int slot = base + __popcll(mask & ((1ull << lane) - 1ull));
                    if (slot < 64) candv[slot] = v;
                }
                base += __popcll(mask);
            }
        }
        __syncthreads();
        const int ncand = base < 64 ? base : 64;

        float bestE = -INFINITY;
        int bestV = VOCAB;
        if (lane < ncand) {
            const int v = candv[lane];
            const int n = kb * VOCAB + v;
            const float* wr_ = w2t + (size_t)n * DMODEL;
            float acc = 0.f;
#pragma unroll 8
            for (int k = 0; k < DMODEL; ++k)
                acc = fmaf(hrow[k], wr_[k], acc);
            bestE = acc + eb2[n] + jax_gumbel((uint64_t)t * VOCAB + v);
            bestV = v;
        }
#pragma unroll
        for (int off = 32; off > 0; off >>= 1) {
            float oe = __shfl_down(bestE, off);
            int ov = __shfl_down(bestV, off);
            if (oe > bestE || (oe == bestE && ov < bestV)) { bestE = oe; bestV = ov; }
        }
        if (lane == 0) tok[t] = bestV;
        __syncthreads();
    }
}

// ----------------- simple sampler (ws-too-small fallback) ------------------
__global__ __launch_bounds__(256)
void sample_tokens_simple(const float* __restrict__ z, int* __restrict__ tokens) {
    const int wave = threadIdx.x >> 6;
    const int lane = threadIdx.x & 63;
    const size_t t = (size_t)blockIdx.x * 4 + wave;
    const float* zr = z + t * VOCAB;
    float zv[8];
    *(float4*)&zv[0] = *(const float4*)&zr[lane * 8];
    *(float4*)&zv[4] = *(const float4*)&zr[lane * 8 + 4];
    const uint64_t ebase = t * (uint64_t)VOCAB + (uint64_t)lane * 8;
    float best = -INFINITY;
    int bestv = 0;
#pragma unroll
    for (int j = 0; j < 8; ++j) {
        float g = jax_gumbel(ebase + j);
        float s = zv[j] + g;
        int v = lane * 8 + j;
        if (s > best || (s == best && v < bestv)) { best = s; bestv = v; }
    }
#pragma unroll
    for (int off = 32; off > 0; off >>= 1) {
        float ob = __shfl_down(best, off);
        int ov = __shfl_down(bestv, off);
        if (ob > best || (ob == best && ov < bestv)) { best = ob; bestv = ov; }
    }
    if (lane == 0) tokens[t] = bestv;
}

__global__ __launch_bounds__(64)
void zero_count(int* p) { if (threadIdx.x == 0) *p = 0; }

// ------------------------- z_q gather (1 block / row) ----------------------
__global__ __launch_bounds__(256)
void gather_zq(const int* __restrict__ tokens, const float* __restrict__ codebook,
               float* __restrict__ zq) {
    const int b = blockIdx.x;
    const int d = threadIdx.x;
    float s = 0.0f;
#pragma unroll
    for (int k = 0; k < KTOK; ++k) {
        int tok = tokens[b * KTOK + k];
        s += codebook[(size_t)(k * VOCAB + tok) * EDIM + d];
    }
    zq[(size_t)b * EDIM + d] = s;
}

// ------------------------------- launcher ----------------------------------
extern "C" void kernel_launch(void* const* d_in, const int* in_sizes, int n_in,
                              void* d_out, int out_size, void* d_ws, size_t ws_size,
                              hipStream_t stream) {
    const float* x   = (const float*)d_in[0];
    const float* ew1 = (const float*)d_in[1];
    const float* eb1 = (const float*)d_in[2];
    const float* ew2 = (const float*)d_in[3];
    const float* eb2 = (const float*)d_in[4];
    const float* cb  = (const float*)d_in[5];
    const float* dw1 = (const float*)d_in[6];
    const float* db1 = (const float*)d_in[7];
    const float* dw2 = (const float*)d_in[8];
    const float* db2 = (const float*)d_in[9];

    float* out = (float*)d_out;
    float* z   = out;
    float* zq  = out + (size_t)BATCH * ZDIM;
    float* rec = zq + (size_t)BATCH * EDIM;

    char* ws = (char*)d_ws;
    // fast2 layout
    float* h    = (float*)(ws);                               // 8 MB
    float* h2   = (float*)(ws + 8388608);                     // 8 MB
    unsigned short* hb   = (unsigned short*)(ws + 16777216);  // 4 MB
    unsigned short* w2bt = (unsigned short*)(ws + 20971520);  // 16 MB
    float* w2t  = (float*)(ws + 37748736);                    // 32 MB
    float4* part = (float4*)(ws + 71303168);                  // 16 MB
    char* tail = ws + 88080384;
    const size_t WS_NEED2 = 88080384 + 1572864 + 256;         // ~89.7 MB
    const bool fast2 = ws_size >= WS_NEED2;
    if (!fast2) tail = ws + 16777216;                         // fallback layout
    int*   tok  = (int*)(tail);
    float* s1v  = (float*)(tail + 524288);
    int*   amb  = (int*)(tail + 1048576);
    int*   cnt  = (int*)(tail + 1572864);

    dim3 blk(256);

    // encoder layer 1 (f32 exact; bf16 copy fused when fast2)
    gemm_f32_64<true ><<<dim3(DMODEL / 64, BATCH / 64), blk, 0, stream>>>(
        x, ew1, eb1, h, fast2 ? hb : (unsigned short*)nullptr,
        BATCH, DMODEL, DMODEL);

    if (fast2) {
        transpose_w2<<<dim3(ZDIM / 32, DMODEL / 32), blk, 0, stream>>>(
            ew2, w2bt, w2t, DMODEL, ZDIM, 1);
        zero_count<<<dim3(1), dim3(64), 0, stream>>>(cnt);
        gemm_mfma_fused<<<dim3(ZDIM / 128, BATCH / 128), blk, 0, stream>>>(
            hb, w2bt, eb2, z, part, BATCH, ZDIM, DMODEL);
        merge_sample<<<dim3(BATCH * KTOK / 256), blk, 0, stream>>>(
            part, tok, s1v, amb, cnt);
        refine_tokens2<<<dim3(4096), dim3(64), 0, stream>>>(
            z, h, w2t, eb2, amb, cnt, s1v, tok);
    } else {
        gemm_f32<false><<<dim3(ZDIM / 128, BATCH / 128), blk, 0, stream>>>(
            h, ew2, eb2, z, BATCH, ZDIM, DMODEL);
        sample_tokens_simple<<<dim3(BATCH * KTOK / 4), blk, 0, stream>>>(z, tok);
    }

    gather_zq<<<dim3(BATCH), blk, 0, stream>>>(tok, cb, zq);

    // decoder (f32 exact)
    gemm_f32_64<true ><<<dim3(DMODEL / 64, BATCH / 64), blk, 0, stream>>>(
        zq, dw1, db1, h2, nullptr, BATCH, DMODEL, EDIM);
    gemm_f32_64<false><<<dim3(DMODEL / 64, BATCH / 64), blk, 0, stream>>>(
        h2, dw2, db2, rec, nullptr, BATCH, DMODEL, DMODEL);
}

// Round 7
// 439.286 us; speedup vs baseline: 1.2002x; 1.2002x over previous
//
#include <hip/hip_runtime.h>
#include <hip/hip_bf16.h>
#include <math.h>
#include <stdint.h>

// ---------------------------------------------------------------------------
// VectorTokenizer: x ->(enc MLP)-> z -> categorical(threefry key(1)) tokens
//   -> z_q = sum of codebook rows -> (dec MLP) -> rec
// Outputs concatenated: z (4096*16384) | z_q (4096*256) | rec (4096*512), f32
//
// R7: revert fusion (occupancy mismatch proved twice). Split kernels:
//  - sampler v3: bits-max pruning. g is monotone in threefry bits, so track
//    (bits_max, z_max, z_min) cheaply, derive conservative bits-threshold,
//    compute the 2-log gumbel only for ~4 candidates/token (bits kept in
//    regs). Ambiguity semantics provably identical; exact refine unchanged.
//  - MFMA GEMM: L2-aware XCD mapping (each XCD owns 4 contiguous by-rows,
//    bx advances every 4 blocks) to kill the 270 MB L2-thrash FETCH.
// ---------------------------------------------------------------------------

#define BATCH 4096
#define KTOK  32
#define VOCAB 512
#define DMODEL 512
#define ZDIM  16384
#define EDIM  256
#define MARGIN 0.03125f

typedef __attribute__((ext_vector_type(8))) short short8v;
typedef __attribute__((ext_vector_type(4))) float f32x4;

// ----------------------- threefry2x32 (JAX-compatible) ---------------------
__device__ __forceinline__ void threefry2x32(uint32_t k0, uint32_t k1,
                                             uint32_t x0, uint32_t x1,
                                             uint32_t& y0, uint32_t& y1) {
    uint32_t ks0 = k0, ks1 = k1, ks2 = k0 ^ k1 ^ 0x1BD11BDAu;
    x0 += ks0; x1 += ks1;
#define TFR(r) { x0 += x1; x1 = __builtin_rotateleft32(x1, r); x1 ^= x0; }
    TFR(13) TFR(15) TFR(26) TFR(6)
    x0 += ks1; x1 += ks2 + 1u;
    TFR(17) TFR(29) TFR(16) TFR(24)
    x0 += ks2; x1 += ks0 + 2u;
    TFR(13) TFR(15) TFR(26) TFR(6)
    x0 += ks0; x1 += ks1 + 3u;
    TFR(17) TFR(29) TFR(16) TFR(24)
    x0 += ks1; x1 += ks2 + 4u;
    TFR(13) TFR(15) TFR(26) TFR(6)
    x0 += ks2; x1 += ks0 + 5u;
#undef TFR
    y0 = x0; y1 = x1;
}

// exact path (refine): matches JAX bit-for-bit
__device__ __forceinline__ float jax_gumbel(uint64_t e) {
    const float TINY = 1.17549435e-38f;
    uint32_t y0, y1;
    threefry2x32(0u, 1u, (uint32_t)(e >> 32), (uint32_t)(e & 0xffffffffull), y0, y1);
    uint32_t bits = y0 ^ y1;
    float u = __uint_as_float(0x3f800000u | (bits >> 9)) - 1.0f;
    u = u * 1.0f + TINY;
    u = fmaxf(TINY, u);
    return -logf(-logf(u));
}

// fast-filter gumbel from raw bits: |g_fast - g_exact| <~ 1e-4 << MARGIN.
// Monotone non-decreasing in bits (within ~hw-log 1e-7 wiggle, covered by
// the 0.004 slack in the pruning threshold).
__device__ __forceinline__ float gumbel_from_bits(uint32_t bits) {
    const float TINY = 1.17549435e-38f;
    const float LN2 = 0.69314718056f;
    float f = __uint_as_float(0x3f800000u | (bits >> 9));  // [1,2)
    float u = f - 1.0f;          // exact (Sterbenz)
    float d = 2.0f - f;          // exact = 1-u
    u = fmaxf(u, TINY);
    float e_hw = -LN2 * __builtin_amdgcn_logf(u);
    float e_poly = d * fmaf(d, fmaf(d, 0.33333333f, 0.5f), 1.0f);
    float e = (d < 0.002f) ? e_poly : e_hw;
    return -LN2 * __builtin_amdgcn_logf(e);
}

__device__ __forceinline__ float fast_gumbel(uint32_t e32) {
    uint32_t y0, y1;
    threefry2x32(0u, 1u, 0u, e32, y0, y1);
    return gumbel_from_bits(y0 ^ y1);
}

__device__ __forceinline__ unsigned short f32_to_bf16_rne(float f) {
    uint32_t u = __float_as_uint(f);
    uint32_t r = (u + 0x7fffu + ((u >> 16) & 1u)) >> 16;
    return (unsigned short)r;
}

// top-2 helpers (tie -> lower index wins, matching jnp.argmax)
__device__ __forceinline__ void top2_push(float& s1, float& s2, int& v1,
                                          float s, int v) {
    if (s > s1 || (s == s1 && v < v1)) { s2 = s1; s1 = s; v1 = v; }
    else s2 = fmaxf(s2, s);
}
__device__ __forceinline__ void top2_merge(float& s1, float& s2, int& v1,
                                           float os1, float os2, int ov1) {
    if (os1 > s1 || (os1 == s1 && ov1 < v1)) {
        s2 = fmaxf(s1, os2);
        s1 = os1; v1 = ov1;
    } else {
        s2 = fmaxf(s2, os1);
    }
}

__device__ __forceinline__ void gload16(const unsigned short* src,
                                        unsigned short* lds_base) {
    __builtin_amdgcn_global_load_lds(
        (const __attribute__((address_space(1))) unsigned int*)src,
        (__attribute__((address_space(3))) unsigned int*)lds_base, 16, 0, 0);
}

// ------------------ tiled f32 GEMM, 64x64 (small layers) -------------------
// k-ascending single fmaf chain per output => bit-exact vs np.
// Optionally also writes bf16 copy of C (enc1 -> hb).
template<bool RELU>
__global__ __launch_bounds__(256)
void gemm_f32_64(const float* __restrict__ A, const float* __restrict__ B,
                 const float* __restrict__ bias, float* __restrict__ C,
                 unsigned short* __restrict__ Cb,
                 int M, int N, int K) {
    constexpr int BK = 16;
    __shared__ __align__(16) float As[BK][68];
    __shared__ __align__(16) float Bs[BK][68];

    const int tid = threadIdx.x;
    const int tx = tid % 16;
    const int ty = tid / 16;
    const int brow = blockIdx.y * 64;
    const int bcol = blockIdx.x * 64;

    float acc[4][4] = {};

    for (int k0 = 0; k0 < K; k0 += BK) {
        {
            int r = tid >> 2, c4 = tid & 3;
            float4 v = *(const float4*)&A[(size_t)(brow + r) * K + k0 + c4 * 4];
            As[c4 * 4 + 0][r] = v.x;
            As[c4 * 4 + 1][r] = v.y;
            As[c4 * 4 + 2][r] = v.z;
            As[c4 * 4 + 3][r] = v.w;
        }
        {
            int r = tid >> 4, c4 = tid & 15;
            *(float4*)&Bs[r][c4 * 4] = *(const float4*)&B[(size_t)(k0 + r) * N + bcol + c4 * 4];
        }
        __syncthreads();

#pragma unroll
        for (int kk = 0; kk < BK; ++kk) {
            float a[4], b[4];
            *(float4*)&a[0] = *(const float4*)&As[kk][ty * 4];
            *(float4*)&b[0] = *(const float4*)&Bs[kk][tx * 4];
#pragma unroll
            for (int i = 0; i < 4; ++i)
#pragma unroll
                for (int j = 0; j < 4; ++j)
                    acc[i][j] = fmaf(a[i], b[j], acc[i][j]);
        }
        __syncthreads();
    }

#pragma unroll
    for (int i = 0; i < 4; ++i) {
        int row = brow + ty * 4 + i;
        int col = bcol + tx * 4;
        float4 v;
        v.x = acc[i][0] + bias[col + 0];
        v.y = acc[i][1] + bias[col + 1];
        v.z = acc[i][2] + bias[col + 2];
        v.w = acc[i][3] + bias[col + 3];
        if (RELU) {
            v.x = fmaxf(v.x, 0.0f); v.y = fmaxf(v.y, 0.0f);
            v.z = fmaxf(v.z, 0.0f); v.w = fmaxf(v.w, 0.0f);
        }
        *(float4*)&C[(size_t)row * N + col] = v;
        if (Cb) {
            ushort4 o;
            o.x = f32_to_bf16_rne(v.x);
            o.y = f32_to_bf16_rne(v.y);
            o.z = f32_to_bf16_rne(v.z);
            o.w = f32_to_bf16_rne(v.w);
            *(ushort4*)&Cb[(size_t)row * N + col] = o;
        }
    }
}

// ---------------- tiled f32 GEMM, 128x128 (fallback big) -------------------
template<bool RELU>
__global__ __launch_bounds__(256)
void gemm_f32(const float* __restrict__ A, const float* __restrict__ B,
              const float* __restrict__ bias, float* __restrict__ C,
              int M, int N, int K) {
    constexpr int BM = 128, BN = 128, BK = 16, TM = 8, TN = 8;
    __shared__ __align__(16) float As[BK][BM + 4];
    __shared__ __align__(16) float Bs[BK][BN + 4];

    const int tid = threadIdx.x;
    const int tx = tid % (BN / TN);
    const int ty = tid / (BN / TN);
    const int brow = blockIdx.y * BM;
    const int bcol = blockIdx.x * BN;

    float acc[TM][TN] = {};

    for (int k0 = 0; k0 < K; k0 += BK) {
#pragma unroll
        for (int f = tid; f < BM * BK / 4; f += 256) {
            int r = f / (BK / 4);
            int c4 = f % (BK / 4);
            float4 v = *(const float4*)&A[(size_t)(brow + r) * K + k0 + c4 * 4];
            As[c4 * 4 + 0][r] = v.x;
            As[c4 * 4 + 1][r] = v.y;
            As[c4 * 4 + 2][r] = v.z;
            As[c4 * 4 + 3][r] = v.w;
        }
#pragma unroll
        for (int f = tid; f < BK * BN / 4; f += 256) {
            int r = f / (BN / 4);
            int c4 = f % (BN / 4);
            *(float4*)&Bs[r][c4 * 4] = *(const float4*)&B[(size_t)(k0 + r) * N + bcol + c4 * 4];
        }
        __syncthreads();

#pragma unroll
        for (int kk = 0; kk < BK; ++kk) {
            float a[TM], b[TN];
            *(float4*)&a[0] = *(const float4*)&As[kk][ty * TM];
            *(float4*)&a[4] = *(const float4*)&As[kk][ty * TM + 4];
            *(float4*)&b[0] = *(const float4*)&Bs[kk][tx * TN];
            *(float4*)&b[4] = *(const float4*)&Bs[kk][tx * TN + 4];
#pragma unroll
            for (int i = 0; i < TM; ++i)
#pragma unroll
                for (int j = 0; j < TN; ++j)
                    acc[i][j] = fmaf(a[i], b[j], acc[i][j]);
        }
        __syncthreads();
    }

#pragma unroll
    for (int i = 0; i < TM; ++i) {
        int row = brow + ty * TM + i;
#pragma unroll
        for (int j = 0; j < TN; j += 4) {
            int col = bcol + tx * TN + j;
            float4 v;
            v.x = acc[i][j + 0] + bias[col + 0];
            v.y = acc[i][j + 1] + bias[col + 1];
            v.z = acc[i][j + 2] + bias[col + 2];
            v.w = acc[i][j + 3] + bias[col + 3];
            if (RELU) {
                v.x = fmaxf(v.x, 0.0f); v.y = fmaxf(v.y, 0.0f);
                v.z = fmaxf(v.z, 0.0f); v.w = fmaxf(v.w, 0.0f);
            }
            *(float4*)&C[(size_t)row * N + col] = v;
        }
    }
}

// ---- f32 [R][C] -> bf16 [C][R] transpose + f32 [C][R] copy ----------------
__global__ __launch_bounds__(256)
void transpose_w2(const float* __restrict__ src, unsigned short* __restrict__ dstb,
                  float* __restrict__ dstf, int R, int C, int writeF) {
    __shared__ float tile[32][33];
    const int c0 = blockIdx.x * 32, r0 = blockIdx.y * 32;
    const int tx = threadIdx.x % 32, ty = threadIdx.x / 32;
#pragma unroll
    for (int i = ty; i < 32; i += 8)
        tile[i][tx] = src[(size_t)(r0 + i) * C + c0 + tx];
    __syncthreads();
#pragma unroll
    for (int i = ty; i < 32; i += 8) {
        float v = tile[tx][i];
        size_t o = (size_t)(c0 + i) * R + r0 + tx;
        dstb[o] = f32_to_bf16_rne(v);
        if (writeF) dstf[o] = v;
    }
}

// ------------------------- bf16 MFMA GEMM (R4 + L2 map) --------------------
// 128x128 tile, BK=32, 4 waves (2x2), wave 64x64 via 4x4 16x16x32 frags.
// L2-aware XCD mapping: xcd = lid&7 owns gridDim.y/8 contiguous by rows;
// bx advances every (rows-per-xcd) blocks -> per-XCD L2 set ~ A 0.5MB + B 2MB.
__global__ __launch_bounds__(256)
void gemm_mfma_bf16(const unsigned short* __restrict__ A,
                    const unsigned short* __restrict__ Bt,
                    const float* __restrict__ bias,
                    float* __restrict__ C,
                    int M, int N, int K) {
    constexpr int BM = 128, BN = 128, BK = 32;
    __shared__ unsigned short As[BM * BK];
    __shared__ unsigned short Bs[BN * BK];

    const int lid = blockIdx.y * gridDim.x + blockIdx.x;
    const int xcd = lid & 7;
    const int kk2 = lid >> 3;
    const int rpx = gridDim.y >> 3;            // by-rows per XCD (32/8 = 4)
    const int by = xcd * rpx + (kk2 % rpx);
    const int bx = kk2 / rpx;

    const int tid = threadIdx.x;
    const int wid = tid >> 6;
    const int lane = tid & 63;
    const int wr = wid >> 1, wc = wid & 1;
    const int l15 = lane & 15, lq = lane >> 4;
    const int brow = by * BM;
    const int bcol = bx * BN;

    const int g1 = tid;
    const int g2 = tid + 256;
    const size_t a1 = (size_t)(brow + (g1 >> 2)) * K + (g1 & 3) * 8;
    const size_t a2 = (size_t)(brow + (g2 >> 2)) * K + (g2 & 3) * 8;
    const size_t b1 = (size_t)(bcol + (g1 >> 2)) * K + (g1 & 3) * 8;
    const size_t b2 = (size_t)(bcol + (g2 >> 2)) * K + (g2 & 3) * 8;
    unsigned short* as_base1 = As + (size_t)wid * 64 * 8;
    unsigned short* as_base2 = As + (size_t)(256 + wid * 64) * 8;
    unsigned short* bs_base1 = Bs + (size_t)wid * 64 * 8;
    unsigned short* bs_base2 = Bs + (size_t)(256 + wid * 64) * 8;

    f32x4 acc[4][4];
#pragma unroll
    for (int m = 0; m < 4; ++m)
#pragma unroll
        for (int n = 0; n < 4; ++n) acc[m][n] = (f32x4){0.f, 0.f, 0.f, 0.f};

    for (int k0 = 0; k0 < K; k0 += BK) {
        gload16(A + a1 + k0, as_base1);
        gload16(A + a2 + k0, as_base2);
        gload16(Bt + b1 + k0, bs_base1);
        gload16(Bt + b2 + k0, bs_base2);
        __syncthreads();

        short8v af[4], bf[4];
#pragma unroll
        for (int m = 0; m < 4; ++m)
            af[m] = *(const short8v*)&As[(wr * 64 + m * 16 + l15) * BK + lq * 8];
#pragma unroll
        for (int n = 0; n < 4; ++n)
            bf[n] = *(const short8v*)&Bs[(wc * 64 + n * 16 + l15) * BK + lq * 8];
#pragma unroll
        for (int m = 0; m < 4; ++m)
#pragma unroll
            for (int n = 0; n < 4; ++n)
                acc[m][n] = __builtin_amdgcn_mfma_f32_16x16x32_bf16(
                    af[m], bf[n], acc[m][n], 0, 0, 0);
        __syncthreads();
    }

#pragma unroll
    for (int m = 0; m < 4; ++m) {
#pragma unroll
        for (int n = 0; n < 4; ++n) {
            int col = bcol + wc * 64 + n * 16 + l15;
            float bv = bias[col];
#pragma unroll
            for (int r = 0; r < 4; ++r) {
                int row = brow + wr * 64 + m * 16 + lq * 4 + r;
                C[(size_t)row * N + col] = acc[m][n][r] + bv;
            }
        }
    }
}

// -------- sampler v3: bits-max pruning (1 wave / token) --------------------
// g = gumbel_from_bits(bits) is monotone in bits. Any v with fast-score
// >= s1 - MARGIN satisfies bits >= bthr where bthr derives conservatively
// from (bits_max, z_max, z_min). Only candidates pay the 2-log gumbel.
__global__ __launch_bounds__(256)
void sample_tokens_prune(const float* __restrict__ z, int* __restrict__ tokens,
                         float* __restrict__ s1v, int* __restrict__ amb,
                         int* __restrict__ ambCount) {
    const int wave = threadIdx.x >> 6;
    const int lane = threadIdx.x & 63;
    const uint32_t t = blockIdx.x * 4 + wave;
    const float* zr = z + (size_t)t * VOCAB;

    uint32_t bb[8];
    float zz[8];
    uint32_t bmax = 0u;
    float zmx = -INFINITY, zmn = INFINITY;
#pragma unroll
    for (int half = 0; half < 2; ++half) {
        const int e0 = half * 256 + lane * 4;
        const float4 zv = *(const float4*)&zr[e0];
        zz[half * 4 + 0] = zv.x; zz[half * 4 + 1] = zv.y;
        zz[half * 4 + 2] = zv.z; zz[half * 4 + 3] = zv.w;
#pragma unroll
        for (int j = 0; j < 4; ++j) {
            uint32_t y0, y1;
            threefry2x32(0u, 1u, 0u, t * (uint32_t)VOCAB + e0 + j, y0, y1);
            const uint32_t b = y0 ^ y1;
            bb[half * 4 + j] = b;
            bmax = b > bmax ? b : bmax;
            zmx = fmaxf(zmx, zz[half * 4 + j]);
            zmn = fminf(zmn, zz[half * 4 + j]);
        }
    }
    // wave-wide reductions
#pragma unroll
    for (int off = 32; off > 0; off >>= 1) {
        uint32_t ob = (uint32_t)__shfl_xor((int)bmax, off);
        bmax = ob > bmax ? ob : bmax;
        zmx = fmaxf(zmx, __shfl_xor(zmx, off));
        zmn = fminf(zmn, __shfl_xor(zmn, off));
    }

    // conservative bits threshold
    const float gmax = gumbel_from_bits(bmax);
    const float delta = (zmx - zmn) + MARGIN + 0.004f;
    const float gstar = gmax - delta;
    const float INVLN2 = 1.4426950408889634f;
    float es = exp2f(-gstar * INVLN2);        // exp(-gstar)
    float us = exp2f(-es * INVLN2);           // exp(-exp(-gstar))
    us = us * (1.0f - 4e-6f) - 4e-6f;         // shift down (safe direction)
    uint32_t bthr = 0u;
    if (us > 0.0f) {
        uint32_t ub = __float_as_uint(1.0f + us) - 0x3f800000u;
        uint32_t bt = ub << 9;
        bthr = bt > 4096u ? bt - 4096u : 0u;  // extra bits-granularity slack
    }

    // candidate evaluation (logs only here; bits reused from regs)
    float s1 = -INFINITY, s2 = -INFINITY;
    int v1 = VOCAB;
#pragma unroll
    for (int idx = 0; idx < 8; ++idx) {
        if (bb[idx] >= bthr) {
            const int v = (idx >> 2) * 256 + lane * 4 + (idx & 3);
            const float s = zz[idx] + gumbel_from_bits(bb[idx]);
            top2_push(s1, s2, v1, s, v);
        }
    }
#pragma unroll
    for (int off = 32; off > 0; off >>= 1) {
        float os1 = __shfl_down(s1, off);
        int ov1 = __shfl_down(v1, off);
        float os2 = __shfl_down(s2, off);
        top2_merge(s1, s2, v1, os1, os2, ov1);
    }
    if (lane == 0) {
        tokens[t] = v1;
        s1v[t] = s1;
        if (s1 - s2 < MARGIN) {
            int idx = atomicAdd(ambCount, 1);
            amb[idx] = (int)t;
        }
    }
}

// ------ refine: w2t f32 rows, ballot-compacted candidates ------------------
__global__ __launch_bounds__(64)
void refine_tokens2(const float* __restrict__ z, const float* __restrict__ h,
                    const float* __restrict__ w2t, const float* __restrict__ eb2,
                    const int* __restrict__ amb, const int* __restrict__ ambCount,
                    const float* __restrict__ s1v, int* __restrict__ tok) {
    __shared__ float hrow[DMODEL];
    __shared__ int candv[64];
    const int cnt = *ambCount;
    const int lane = threadIdx.x;

    for (int i = blockIdx.x; i < cnt; i += gridDim.x) {
        const int t = amb[i];
        const int b = t >> 5;
        const int kb = t & 31;
        const float* zr = z + (size_t)t * VOCAB;
        const float s1 = s1v[t];

        {
            float4 hv0 = *(const float4*)&h[(size_t)b * DMODEL + lane * 8];
            float4 hv1 = *(const float4*)&h[(size_t)b * DMODEL + lane * 8 + 4];
            *(float4*)&hrow[lane * 8] = hv0;
            *(float4*)&hrow[lane * 8 + 4] = hv1;
        }

        int base = 0;
#pragma unroll
        for (int half = 0; half < 2; ++half) {
            int e0 = half * 256 + lane * 4;
            float4 zv = *(const float4*)&zr[e0];
            float zs[4] = {zv.x, zv.y, zv.z, zv.w};
#pragma unroll
            for (int j = 0; j < 4; ++j) {
                int v = e0 + j;
                float s = zs[j] + fast_gumbel((uint32_t)t * VOCAB + v);
                bool pred = (s >= s1 - MARGIN);
                unsigned long long mask = __ballot(pred);
                if (pred) {
                    int slot = base + __popcll(mask & ((1ull << lane) - 1ull));
                    if (slot < 64) candv[slot] = v;
                }
                base += __popcll(mask);
            }
        }
        __syncthreads();
        const int ncand = base < 64 ? base : 64;

        float bestE = -INFINITY;
        int bestV = VOCAB;
        if (lane < ncand) {
            const int v = candv[lane];
            const int n = kb * VOCAB + v;
            const float* wr_ = w2t + (size_t)n * DMODEL;
            float acc = 0.f;
#pragma unroll 8
            for (int k = 0; k < DMODEL; ++k)
                acc = fmaf(hrow[k], wr_[k], acc);
            bestE = acc + eb2[n] + jax_gumbel((uint64_t)t * VOCAB + v);
            bestV = v;
        }
#pragma unroll
        for (int off = 32; off > 0; off >>= 1) {
            float oe = __shfl_down(bestE, off);
            int ov = __shfl_down(bestV, off);
            if (oe > bestE || (oe == bestE && ov < bestV)) { bestE = oe; bestV = ov; }
        }
        if (lane == 0) tok[t] = bestV;
        __syncthreads();
    }
}

// ----------------- simple sampler (ws-too-small fallback) ------------------
__global__ __launch_bounds__(256)
void sample_tokens_simple(const float* __restrict__ z, int* __restrict__ tokens) {
    const int wave = threadIdx.x >> 6;
    const int lane = threadIdx.x & 63;
    const size_t t = (size_t)blockIdx.x * 4 + wave;
    const float* zr = z + t * VOCAB;
    float zv[8];
    *(float4*)&zv[0] = *(const float4*)&zr[lane * 8];
    *(float4*)&zv[4] = *(const float4*)&zr[lane * 8 + 4];
    const uint64_t ebase = t * (uint64_t)VOCAB + (uint64_t)lane * 8;
    float best = -INFINITY;
    int bestv = 0;
#pragma unroll
    for (int j = 0; j < 8; ++j) {
        float g = jax_gumbel(ebase + j);
        float s = zv[j] + g;
        int v = lane * 8 + j;
        if (s > best || (s == best && v < bestv)) { best = s; bestv = v; }
    }
#pragma unroll
    for (int off = 32; off > 0; off >>= 1) {
        float ob = __shfl_down(best, off);
        int ov = __shfl_down(bestv, off);
        if (ob > best || (ob == best && ov < bestv)) { best = ob; bestv = ov; }
    }
    if (lane == 0) tokens[t] = bestv;
}

__global__ __launch_bounds__(64)
void zero_count(int* p) { if (threadIdx.x == 0) *p = 0; }

// ------------------------- z_q gather (1 block / row) ----------------------
__global__ __launch_bounds__(256)
void gather_zq(const int* __restrict__ tokens, const float* __restrict__ codebook,
               float* __restrict__ zq) {
    const int b = blockIdx.x;
    const int d = threadIdx.x;
    float s = 0.0f;
#pragma unroll
    for (int k = 0; k < KTOK; ++k) {
        int tok = tokens[b * KTOK + k];
        s += codebook[(size_t)(k * VOCAB + tok) * EDIM + d];
    }
    zq[(size_t)b * EDIM + d] = s;
}

// ------------------------------- launcher ----------------------------------
extern "C" void kernel_launch(void* const* d_in, const int* in_sizes, int n_in,
                              void* d_out, int out_size, void* d_ws, size_t ws_size,
                              hipStream_t stream) {
    const float* x   = (const float*)d_in[0];
    const float* ew1 = (const float*)d_in[1];
    const float* eb1 = (const float*)d_in[2];
    const float* ew2 = (const float*)d_in[3];
    const float* eb2 = (const float*)d_in[4];
    const float* cb  = (const float*)d_in[5];
    const float* dw1 = (const float*)d_in[6];
    const float* db1 = (const float*)d_in[7];
    const float* dw2 = (const float*)d_in[8];
    const float* db2 = (const float*)d_in[9];

    float* out = (float*)d_out;
    float* z   = out;
    float* zq  = out + (size_t)BATCH * ZDIM;
    float* rec = zq + (size_t)BATCH * EDIM;

    char* ws = (char*)d_ws;
    float* h    = (float*)(ws);                               // 8 MB
    float* h2   = (float*)(ws + 8388608);                     // 8 MB
    unsigned short* hb   = (unsigned short*)(ws + 16777216);  // 4 MB
    unsigned short* w2bt = (unsigned short*)(ws + 20971520);  // 16 MB
    float* w2t  = (float*)(ws + 37748736);                    // 32 MB
    char* tail = ws + 71303168;
    const size_t WS_NEED2 = 71303168 + 1572864 + 256;         // ~72.9 MB
    const bool fast2 = ws_size >= WS_NEED2;
    if (!fast2) tail = ws + 16777216;                         // fallback layout
    int*   tok  = (int*)(tail);
    float* s1v  = (float*)(tail + 524288);
    int*   amb  = (int*)(tail + 1048576);
    int*   cnt  = (int*)(tail + 1572864);

    dim3 blk(256);

    // encoder layer 1 (f32 exact; bf16 copy fused when fast2)
    gemm_f32_64<true ><<<dim3(DMODEL / 64, BATCH / 64), blk, 0, stream>>>(
        x, ew1, eb1, h, fast2 ? hb : (unsigned short*)nullptr,
        BATCH, DMODEL, DMODEL);

    if (fast2) {
        transpose_w2<<<dim3(ZDIM / 32, DMODEL / 32), blk, 0, stream>>>(
            ew2, w2bt, w2t, DMODEL, ZDIM, 1);
        zero_count<<<dim3(1), dim3(64), 0, stream>>>(cnt);
        gemm_mfma_bf16<<<dim3(ZDIM / 128, BATCH / 128), blk, 0, stream>>>(
            hb, w2bt, eb2, z, BATCH, ZDIM, DMODEL);
        sample_tokens_prune<<<dim3(BATCH * KTOK / 4), blk, 0, stream>>>(
            z, tok, s1v, amb, cnt);
        refine_tokens2<<<dim3(4096), dim3(64), 0, stream>>>(
            z, h, w2t, eb2, amb, cnt, s1v, tok);
    } else {
        gemm_f32<false><<<dim3(ZDIM / 128, BATCH / 128), blk, 0, stream>>>(
            h, ew2, eb2, z, BATCH, ZDIM, DMODEL);
        sample_tokens_simple<<<dim3(BATCH * KTOK / 4), blk, 0, stream>>>(z, tok);
    }

    gather_zq<<<dim3(BATCH), blk, 0, stream>>>(tok, cb, zq);

    // decoder (f32 exact)
    gemm_f32_64<true ><<<dim3(DMODEL / 64, BATCH / 64), blk, 0, stream>>>(
        zq, dw1, db1, h2, nullptr, BATCH, DMODEL, EDIM);
    gemm_f32_64<false><<<dim3(DMODEL / 64, BATCH / 64), blk, 0, stream>>>(
        h2, dw2, db2, rec, nullptr, BATCH, DMODEL, DMODEL);
}

// Round 8
// 435.136 us; speedup vs baseline: 1.2117x; 1.0095x over previous
//
#include <hip/hip_runtime.h>
#include <hip/hip_bf16.h>
#include <math.h>
#include <stdint.h>

// ---------------------------------------------------------------------------
// VectorTokenizer: x ->(enc MLP)-> z -> categorical(threefry key(1)) tokens
//   -> z_q = sum of codebook rows -> (dec MLP) -> rec
// Outputs concatenated: z (4096*16384) | z_q (4096*256) | rec (4096*512), f32
//
// R8: (1) sampler v4 — manual 4-way-interleaved threefry chains (named
// scalars, no arrays) to break the register-starved serial-chain bottleneck;
// logs kept (trans pipe is free). (2) big GEMM double-buffered LDS (stage
// k+1 before compute k, ONE barrier per K-step) — at K=512 the old 2-barrier
// structure was drain-bound. Exact refine / margin semantics unchanged.
// ---------------------------------------------------------------------------

#define BATCH 4096
#define KTOK  32
#define VOCAB 512
#define DMODEL 512
#define ZDIM  16384
#define EDIM  256
#define MARGIN 0.03125f

typedef __attribute__((ext_vector_type(8))) short short8v;
typedef __attribute__((ext_vector_type(4))) float f32x4;

// ----------------------- threefry2x32 (JAX-compatible) ---------------------
__device__ __forceinline__ void threefry2x32(uint32_t k0, uint32_t k1,
                                             uint32_t x0, uint32_t x1,
                                             uint32_t& y0, uint32_t& y1) {
    uint32_t ks0 = k0, ks1 = k1, ks2 = k0 ^ k1 ^ 0x1BD11BDAu;
    x0 += ks0; x1 += ks1;
#define TFR(r) { x0 += x1; x1 = __builtin_rotateleft32(x1, r); x1 ^= x0; }
    TFR(13) TFR(15) TFR(26) TFR(6)
    x0 += ks1; x1 += ks2 + 1u;
    TFR(17) TFR(29) TFR(16) TFR(24)
    x0 += ks2; x1 += ks0 + 2u;
    TFR(13) TFR(15) TFR(26) TFR(6)
    x0 += ks0; x1 += ks1 + 3u;
    TFR(17) TFR(29) TFR(16) TFR(24)
    x0 += ks1; x1 += ks2 + 4u;
    TFR(13) TFR(15) TFR(26) TFR(6)
    x0 += ks2; x1 += ks0 + 5u;
#undef TFR
    y0 = x0; y1 = x1;
}

// 4 consecutive counters (key = (0,1), high word 0), manually interleaved so
// the 4 chains pipeline at issue rate instead of dependent-op latency.
__device__ __forceinline__ void threefry4x(uint32_t e,
                                           uint32_t& o0, uint32_t& o1,
                                           uint32_t& o2, uint32_t& o3) {
    const uint32_t KS2 = 0x1BD11BDBu;            // 0^1^0x1BD11BDA
    uint32_t xa = 0u, ya = e + 1u;               // x1 init = e_i + ks1
    uint32_t xb = 0u, yb = e + 2u;
    uint32_t xc = 0u, yc = e + 3u;
    uint32_t xd = 0u, yd = e + 4u;
#define RR(r) \
    xa += ya; xb += yb; xc += yc; xd += yd; \
    ya = __builtin_rotateleft32(ya, r) ^ xa; \
    yb = __builtin_rotateleft32(yb, r) ^ xb; \
    yc = __builtin_rotateleft32(yc, r) ^ xc; \
    yd = __builtin_rotateleft32(yd, r) ^ xd;
    RR(13) RR(15) RR(26) RR(6)
    xa += 1u; xb += 1u; xc += 1u; xd += 1u;
    ya += KS2 + 1u; yb += KS2 + 1u; yc += KS2 + 1u; yd += KS2 + 1u;
    RR(17) RR(29) RR(16) RR(24)
    xa += KS2; xb += KS2; xc += KS2; xd += KS2;
    ya += 2u; yb += 2u; yc += 2u; yd += 2u;
    RR(13) RR(15) RR(26) RR(6)
    ya += 4u; yb += 4u; yc += 4u; yd += 4u;      // ks0=0; ks1+3 = 4
    RR(17) RR(29) RR(16) RR(24)
    xa += 1u; xb += 1u; xc += 1u; xd += 1u;
    ya += KS2 + 4u; yb += KS2 + 4u; yc += KS2 + 4u; yd += KS2 + 4u;
    RR(13) RR(15) RR(26) RR(6)
    xa += KS2; xb += KS2; xc += KS2; xd += KS2;
    ya += 5u; yb += 5u; yc += 5u; yd += 5u;
#undef RR
    o0 = xa ^ ya; o1 = xb ^ yb; o2 = xc ^ yc; o3 = xd ^ yd;
}

// exact path (refine): matches JAX bit-for-bit
__device__ __forceinline__ float jax_gumbel(uint64_t e) {
    const float TINY = 1.17549435e-38f;
    uint32_t y0, y1;
    threefry2x32(0u, 1u, (uint32_t)(e >> 32), (uint32_t)(e & 0xffffffffull), y0, y1);
    uint32_t bits = y0 ^ y1;
    float u = __uint_as_float(0x3f800000u | (bits >> 9)) - 1.0f;
    u = u * 1.0f + TINY;
    u = fmaxf(TINY, u);
    return -logf(-logf(u));
}

// fast-filter gumbel from raw bits: |g_fast - g_exact| <~ 1e-4 << MARGIN
__device__ __forceinline__ float gumbel_from_bits(uint32_t bits) {
    const float TINY = 1.17549435e-38f;
    const float LN2 = 0.69314718056f;
    float f = __uint_as_float(0x3f800000u | (bits >> 9));  // [1,2)
    float u = f - 1.0f;          // exact (Sterbenz)
    float d = 2.0f - f;          // exact = 1-u
    u = fmaxf(u, TINY);
    float e_hw = -LN2 * __builtin_amdgcn_logf(u);
    float e_poly = d * fmaf(d, fmaf(d, 0.33333333f, 0.5f), 1.0f);
    float e = (d < 0.002f) ? e_poly : e_hw;
    return -LN2 * __builtin_amdgcn_logf(e);
}

__device__ __forceinline__ float fast_gumbel(uint32_t e32) {
    uint32_t y0, y1;
    threefry2x32(0u, 1u, 0u, e32, y0, y1);
    return gumbel_from_bits(y0 ^ y1);
}

__device__ __forceinline__ unsigned short f32_to_bf16_rne(float f) {
    uint32_t u = __float_as_uint(f);
    uint32_t r = (u + 0x7fffu + ((u >> 16) & 1u)) >> 16;
    return (unsigned short)r;
}

// top-2 helpers (tie -> lower index wins, matching jnp.argmax)
__device__ __forceinline__ void top2_push(float& s1, float& s2, int& v1,
                                          float s, int v) {
    if (s > s1 || (s == s1 && v < v1)) { s2 = s1; s1 = s; v1 = v; }
    else s2 = fmaxf(s2, s);
}
__device__ __forceinline__ void top2_merge(float& s1, float& s2, int& v1,
                                           float os1, float os2, int ov1) {
    if (os1 > s1 || (os1 == s1 && ov1 < v1)) {
        s2 = fmaxf(s1, os2);
        s1 = os1; v1 = ov1;
    } else {
        s2 = fmaxf(s2, os1);
    }
}

__device__ __forceinline__ void gload16(const unsigned short* src,
                                        unsigned short* lds_base) {
    __builtin_amdgcn_global_load_lds(
        (const __attribute__((address_space(1))) unsigned int*)src,
        (__attribute__((address_space(3))) unsigned int*)lds_base, 16, 0, 0);
}

// ------------------ tiled f32 GEMM, 64x64 (small layers) -------------------
// k-ascending single fmaf chain per output => bit-exact vs np.
// Optionally also writes bf16 copy of C (enc1 -> hb).
template<bool RELU>
__global__ __launch_bounds__(256)
void gemm_f32_64(const float* __restrict__ A, const float* __restrict__ B,
                 const float* __restrict__ bias, float* __restrict__ C,
                 unsigned short* __restrict__ Cb,
                 int M, int N, int K) {
    constexpr int BK = 16;
    __shared__ __align__(16) float As[BK][68];
    __shared__ __align__(16) float Bs[BK][68];

    const int tid = threadIdx.x;
    const int tx = tid % 16;
    const int ty = tid / 16;
    const int brow = blockIdx.y * 64;
    const int bcol = blockIdx.x * 64;

    float acc[4][4] = {};

    for (int k0 = 0; k0 < K; k0 += BK) {
        {
            int r = tid >> 2, c4 = tid & 3;
            float4 v = *(const float4*)&A[(size_t)(brow + r) * K + k0 + c4 * 4];
            As[c4 * 4 + 0][r] = v.x;
            As[c4 * 4 + 1][r] = v.y;
            As[c4 * 4 + 2][r] = v.z;
            As[c4 * 4 + 3][r] = v.w;
        }
        {
            int r = tid >> 4, c4 = tid & 15;
            *(float4*)&Bs[r][c4 * 4] = *(const float4*)&B[(size_t)(k0 + r) * N + bcol + c4 * 4];
        }
        __syncthreads();

#pragma unroll
        for (int kk = 0; kk < BK; ++kk) {
            float a[4], b[4];
            *(float4*)&a[0] = *(const float4*)&As[kk][ty * 4];
            *(float4*)&b[0] = *(const float4*)&Bs[kk][tx * 4];
#pragma unroll
            for (int i = 0; i < 4; ++i)
#pragma unroll
                for (int j = 0; j < 4; ++j)
                    acc[i][j] = fmaf(a[i], b[j], acc[i][j]);
        }
        __syncthreads();
    }

#pragma unroll
    for (int i = 0; i < 4; ++i) {
        int row = brow + ty * 4 + i;
        int col = bcol + tx * 4;
        float4 v;
        v.x = acc[i][0] + bias[col + 0];
        v.y = acc[i][1] + bias[col + 1];
        v.z = acc[i][2] + bias[col + 2];
        v.w = acc[i][3] + bias[col + 3];
        if (RELU) {
            v.x = fmaxf(v.x, 0.0f); v.y = fmaxf(v.y, 0.0f);
            v.z = fmaxf(v.z, 0.0f); v.w = fmaxf(v.w, 0.0f);
        }
        *(float4*)&C[(size_t)row * N + col] = v;
        if (Cb) {
            ushort4 o;
            o.x = f32_to_bf16_rne(v.x);
            o.y = f32_to_bf16_rne(v.y);
            o.z = f32_to_bf16_rne(v.z);
            o.w = f32_to_bf16_rne(v.w);
            *(ushort4*)&Cb[(size_t)row * N + col] = o;
        }
    }
}

// ---------------- tiled f32 GEMM, 128x128 (fallback big) -------------------
template<bool RELU>
__global__ __launch_bounds__(256)
void gemm_f32(const float* __restrict__ A, const float* __restrict__ B,
              const float* __restrict__ bias, float* __restrict__ C,
              int M, int N, int K) {
    constexpr int BM = 128, BN = 128, BK = 16, TM = 8, TN = 8;
    __shared__ __align__(16) float As[BK][BM + 4];
    __shared__ __align__(16) float Bs[BK][BN + 4];

    const int tid = threadIdx.x;
    const int tx = tid % (BN / TN);
    const int ty = tid / (BN / TN);
    const int brow = blockIdx.y * BM;
    const int bcol = blockIdx.x * BN;

    float acc[TM][TN] = {};

    for (int k0 = 0; k0 < K; k0 += BK) {
#pragma unroll
        for (int f = tid; f < BM * BK / 4; f += 256) {
            int r = f / (BK / 4);
            int c4 = f % (BK / 4);
            float4 v = *(const float4*)&A[(size_t)(brow + r) * K + k0 + c4 * 4];
            As[c4 * 4 + 0][r] = v.x;
            As[c4 * 4 + 1][r] = v.y;
            As[c4 * 4 + 2][r] = v.z;
            As[c4 * 4 + 3][r] = v.w;
        }
#pragma unroll
        for (int f = tid; f < BK * BN / 4; f += 256) {
            int r = f / (BN / 4);
            int c4 = f % (BN / 4);
            *(float4*)&Bs[r][c4 * 4] = *(const float4*)&B[(size_t)(k0 + r) * N + bcol + c4 * 4];
        }
        __syncthreads();

#pragma unroll
        for (int kk = 0; kk < BK; ++kk) {
            float a[TM], b[TN];
            *(float4*)&a[0] = *(const float4*)&As[kk][ty * TM];
            *(float4*)&a[4] = *(const float4*)&As[kk][ty * TM + 4];
            *(float4*)&b[0] = *(const float4*)&Bs[kk][tx * TN];
            *(float4*)&b[4] = *(const float4*)&Bs[kk][tx * TN + 4];
#pragma unroll
            for (int i = 0; i < TM; ++i)
#pragma unroll
                for (int j = 0; j < TN; ++j)
                    acc[i][j] = fmaf(a[i], b[j], acc[i][j]);
        }
        __syncthreads();
    }

#pragma unroll
    for (int i = 0; i < TM; ++i) {
        int row = brow + ty * TM + i;
#pragma unroll
        for (int j = 0; j < TN; j += 4) {
            int col = bcol + tx * TN + j;
            float4 v;
            v.x = acc[i][j + 0] + bias[col + 0];
            v.y = acc[i][j + 1] + bias[col + 1];
            v.z = acc[i][j + 2] + bias[col + 2];
            v.w = acc[i][j + 3] + bias[col + 3];
            if (RELU) {
                v.x = fmaxf(v.x, 0.0f); v.y = fmaxf(v.y, 0.0f);
                v.z = fmaxf(v.z, 0.0f); v.w = fmaxf(v.w, 0.0f);
            }
            *(float4*)&C[(size_t)row * N + col] = v;
        }
    }
}

// ---- f32 [R][C] -> bf16 [C][R] transpose + f32 [C][R] copy ----------------
__global__ __launch_bounds__(256)
void transpose_w2(const float* __restrict__ src, unsigned short* __restrict__ dstb,
                  float* __restrict__ dstf, int R, int C, int writeF) {
    __shared__ float tile[32][33];
    const int c0 = blockIdx.x * 32, r0 = blockIdx.y * 32;
    const int tx = threadIdx.x % 32, ty = threadIdx.x / 32;
#pragma unroll
    for (int i = ty; i < 32; i += 8)
        tile[i][tx] = src[(size_t)(r0 + i) * C + c0 + tx];
    __syncthreads();
#pragma unroll
    for (int i = ty; i < 32; i += 8) {
        float v = tile[tx][i];
        size_t o = (size_t)(c0 + i) * R + r0 + tx;
        dstb[o] = f32_to_bf16_rne(v);
        if (writeF) dstf[o] = v;
    }
}

// ---------------- bf16 MFMA GEMM, double-buffered LDS ----------------------
// 128x128 tile, BK=32, 4 waves (2x2), wave 64x64 via 4x4 16x16x32 frags.
// Stage tile k+1 into buf^1 BEFORE computing tile k; ONE barrier per K-step
// (T3-minimum). L2-aware XCD mapping: xcd owns 4 contiguous by-rows.
__global__ __launch_bounds__(256)
void gemm_mfma_bf16(const unsigned short* __restrict__ A,
                    const unsigned short* __restrict__ Bt,
                    const float* __restrict__ bias,
                    float* __restrict__ C,
                    int M, int N, int K) {
    constexpr int BM = 128, BN = 128, BK = 32;
    constexpr int TSZ = BM * BK;                 // 4096 elems / buffer
    __shared__ unsigned short As[2 * TSZ];
    __shared__ unsigned short Bs[2 * TSZ];

    const int lid = blockIdx.y * gridDim.x + blockIdx.x;
    const int xcd = lid & 7;
    const int kk2 = lid >> 3;
    const int rpx = gridDim.y >> 3;              // by-rows per XCD (32/8 = 4)
    const int by = xcd * rpx + (kk2 % rpx);
    const int bx = kk2 / rpx;

    const int tid = threadIdx.x;
    const int wid = tid >> 6;
    const int lane = tid & 63;
    const int wr = wid >> 1, wc = wid & 1;
    const int l15 = lane & 15, lq = lane >> 4;
    const int brow = by * BM;
    const int bcol = bx * BN;

    const int g1 = tid;
    const int g2 = tid + 256;
    const size_t a1 = (size_t)(brow + (g1 >> 2)) * K + (g1 & 3) * 8;
    const size_t a2 = (size_t)(brow + (g2 >> 2)) * K + (g2 & 3) * 8;
    const size_t b1 = (size_t)(bcol + (g1 >> 2)) * K + (g1 & 3) * 8;
    const size_t b2 = (size_t)(bcol + (g2 >> 2)) * K + (g2 & 3) * 8;
    const int asOff1 = wid * 64 * 8;
    const int asOff2 = (256 + wid * 64) * 8;

    f32x4 acc[4][4];
#pragma unroll
    for (int m = 0; m < 4; ++m)
#pragma unroll
        for (int n = 0; n < 4; ++n) acc[m][n] = (f32x4){0.f, 0.f, 0.f, 0.f};

    const int NK = K / BK;                       // 16
    // prologue: stage tile 0 into buf 0
    gload16(A + a1, As + asOff1);
    gload16(A + a2, As + asOff2);
    gload16(Bt + b1, Bs + asOff1);
    gload16(Bt + b2, Bs + asOff2);
    __syncthreads();

    int buf = 0;
    for (int kt = 0; kt < NK; ++kt) {
        // issue next-tile stage into the other buffer (no wait)
        if (kt + 1 < NK) {
            const int k0 = (kt + 1) * BK;
            const int o = (buf ^ 1) * TSZ;
            gload16(A + a1 + k0, As + o + asOff1);
            gload16(A + a2 + k0, As + o + asOff2);
            gload16(Bt + b1 + k0, Bs + o + asOff1);
            gload16(Bt + b2 + k0, Bs + o + asOff2);
        }
        // compute on current buffer
        const int cb = buf * TSZ;
        short8v af[4], bf[4];
#pragma unroll
        for (int m = 0; m < 4; ++m)
            af[m] = *(const short8v*)&As[cb + (wr * 64 + m * 16 + l15) * BK + lq * 8];
#pragma unroll
        for (int n = 0; n < 4; ++n)
            bf[n] = *(const short8v*)&Bs[cb + (wc * 64 + n * 16 + l15) * BK + lq * 8];
#pragma unroll
        for (int m = 0; m < 4; ++m)
#pragma unroll
            for (int n = 0; n < 4; ++n)
                acc[m][n] = __builtin_amdgcn_mfma_f32_16x16x32_bf16(
                    af[m], bf[n], acc[m][n], 0, 0, 0);
        __syncthreads();    // publishes buf^1, and guards buf reuse next iter
        buf ^= 1;
    }

#pragma unroll
    for (int m = 0; m < 4; ++m) {
#pragma unroll
        for (int n = 0; n < 4; ++n) {
            int col = bcol + wc * 64 + n * 16 + l15;
            float bv = bias[col];
#pragma unroll
            for (int r = 0; r < 4; ++r) {
                int row = brow + wr * 64 + m * 16 + lq * 4 + r;
                C[(size_t)row * N + col] = acc[m][n][r] + bv;
            }
        }
    }
}

// -------- sampler v4: 4-way-ILP threefry, streaming top-2 ------------------
// 1 wave / token; lane covers elements lane*4..+3 and 256+lane*4..+3.
// Gumbel values identical to the R4/R7 filter (same bits, same math).
__global__ __launch_bounds__(256)
void sample_tokens_ilp(const float* __restrict__ z, int* __restrict__ tokens,
                       float* __restrict__ s1v, int* __restrict__ amb,
                       int* __restrict__ ambCount) {
    const int wave = threadIdx.x >> 6;
    const int lane = threadIdx.x & 63;
    const uint32_t t = blockIdx.x * 4 + wave;
    const float* zr = z + (size_t)t * VOCAB;

    float s1 = -INFINITY, s2 = -INFINITY;
    int v1 = VOCAB;
#pragma unroll
    for (int half = 0; half < 2; ++half) {
        const int e0 = half * 256 + lane * 4;
        const float4 zv = *(const float4*)&zr[e0];
        uint32_t b0, b1, b2, b3;
        threefry4x(t * (uint32_t)VOCAB + (uint32_t)e0, b0, b1, b2, b3);
        const float g0 = gumbel_from_bits(b0);
        const float g1 = gumbel_from_bits(b1);
        const float g2 = gumbel_from_bits(b2);
        const float g3 = gumbel_from_bits(b3);
        top2_push(s1, s2, v1, zv.x + g0, e0 + 0);
        top2_push(s1, s2, v1, zv.y + g1, e0 + 1);
        top2_push(s1, s2, v1, zv.z + g2, e0 + 2);
        top2_push(s1, s2, v1, zv.w + g3, e0 + 3);
    }
#pragma unroll
    for (int off = 32; off > 0; off >>= 1) {
        float os1 = __shfl_xor(s1, off);
        int ov1 = __shfl_xor(v1, off);
        float os2 = __shfl_xor(s2, off);
        top2_merge(s1, s2, v1, os1, os2, ov1);
    }
    if (lane == 0) {
        tokens[t] = v1;
        s1v[t] = s1;
        if (s1 - s2 < MARGIN) {
            int idx = atomicAdd(ambCount, 1);
            amb[idx] = (int)t;
        }
    }
}

// ------ refine: w2t f32 rows, ballot-compacted candidates ------------------
__global__ __launch_bounds__(64)
void refine_tokens2(const float* __restrict__ z, const float* __restrict__ h,
                    const float* __restrict__ w2t, const float* __restrict__ eb2,
                    const int* __restrict__ amb, const int* __restrict__ ambCount,
                    const float* __restrict__ s1v, int* __restrict__ tok) {
    __shared__ float hrow[DMODEL];
    __shared__ int candv[64];
    const int cnt = *ambCount;
    const int lane = threadIdx.x;

    for (int i = blockIdx.x; i < cnt; i += gridDim.x) {
        const int t = amb[i];
        const int b = t >> 5;
        const int kb = t & 31;
        const float* zr = z + (size_t)t * VOCAB;
        const float s1 = s1v[t];

        {
            float4 hv0 = *(const float4*)&h[(size_t)b * DMODEL + lane * 8];
            float4 hv1 = *(const float4*)&h[(size_t)b * DMODEL + lane * 8 + 4];
            *(float4*)&hrow[lane * 8] = hv0;
            *(float4*)&hrow[lane * 8 + 4] = hv1;
        }

        int base = 0;
#pragma unroll
        for (int half = 0; half < 2; ++half) {
            int e0 = half * 256 + lane * 4;
            float4 zv = *(const float4*)&zr[e0];
            float zs[4] = {zv.x, zv.y, zv.z, zv.w};
#pragma unroll
            for (int j = 0; j < 4; ++j) {
                int v = e0 + j;
                float s = zs[j] + fast_gumbel((uint32_t)t * VOCAB + v);
                bool pred = (s >= s1 - MARGIN);
                unsigned long long mask = __ballot(pred);
                if (pred) {
                    int slot = base + __popcll(mask & ((1ull << lane) - 1ull));
                    if (slot < 64) candv[slot] = v;
                }
                base += __popcll(mask);
            }
        }
        __syncthreads();
        const int ncand = base < 64 ? base : 64;

        float bestE = -INFINITY;
        int bestV = VOCAB;
        if (lane < ncand) {
            const int v = candv[lane];
            const int n = kb * VOCAB + v;
            const float* wr_ = w2t + (size_t)n * DMODEL;
            float acc = 0.f;
#pragma unroll 8
            for (int k = 0; k < DMODEL; ++k)
                acc = fmaf(hrow[k], wr_[k], acc);
            bestE = acc + eb2[n] + jax_gumbel((uint64_t)t * VOCAB + v);
            bestV = v;
        }
#pragma unroll
        for (int off = 32; off > 0; off >>= 1) {
            float oe = __shfl_down(bestE, off);
            int ov = __shfl_down(bestV, off);
            if (oe > bestE || (oe == bestE && ov < bestV)) { bestE = oe; bestV = ov; }
        }
        if (lane == 0) tok[t] = bestV;
        __syncthreads();
    }
}

// ----------------- simple sampler (ws-too-small fallback) ------------------
__global__ __launch_bounds__(256)
void sample_tokens_simple(const float* __restrict__ z, int* __restrict__ tokens) {
    const int wave = threadIdx.x >> 6;
    const int lane = threadIdx.x & 63;
    const size_t t = (size_t)blockIdx.x * 4 + wave;
    const float* zr = z + t * VOCAB;
    float zv[8];
    *(float4*)&zv[0] = *(const float4*)&zr[lane * 8];
    *(float4*)&zv[4] = *(const float4*)&zr[lane * 8 + 4];
    const uint64_t ebase = t * (uint64_t)VOCAB + (uint64_t)lane * 8;
    float best = -INFINITY;
    int bestv = 0;
#pragma unroll
    for (int j = 0; j < 8; ++j) {
        float g = jax_gumbel(ebase + j);
        float s = zv[j] + g;
        int v = lane * 8 + j;
        if (s > best || (s == best && v < bestv)) { best = s; bestv = v; }
    }
#pragma unroll
    for (int off = 32; off > 0; off >>= 1) {
        float ob = __shfl_down(best, off);
        int ov = __shfl_down(bestv, off);
        if (ob > best || (ob == best && ov < bestv)) { best = ob; bestv = ov; }
    }
    if (lane == 0) tokens[t] = bestv;
}

__global__ __launch_bounds__(64)
void zero_count(int* p) { if (threadIdx.x == 0) *p = 0; }

// ------------------------- z_q gather (1 block / row) ----------------------
__global__ __launch_bounds__(256)
void gather_zq(const int* __restrict__ tokens, const float* __restrict__ codebook,
               float* __restrict__ zq) {
    const int b = blockIdx.x;
    const int d = threadIdx.x;
    float s = 0.0f;
#pragma unroll
    for (int k = 0; k < KTOK; ++k) {
        int tok = tokens[b * KTOK + k];
        s += codebook[(size_t)(k * VOCAB + tok) * EDIM + d];
    }
    zq[(size_t)b * EDIM + d] = s;
}

// ------------------------------- launcher ----------------------------------
extern "C" void kernel_launch(void* const* d_in, const int* in_sizes, int n_in,
                              void* d_out, int out_size, void* d_ws, size_t ws_size,
                              hipStream_t stream) {
    const float* x   = (const float*)d_in[0];
    const float* ew1 = (const float*)d_in[1];
    const float* eb1 = (const float*)d_in[2];
    const float* ew2 = (const float*)d_in[3];
    const float* eb2 = (const float*)d_in[4];
    const float* cb  = (const float*)d_in[5];
    const float* dw1 = (const float*)d_in[6];
    const float* db1 = (const float*)d_in[7];
    const float* dw2 = (const float*)d_in[8];
    const float* db2 = (const float*)d_in[9];

    float* out = (float*)d_out;
    float* z   = out;
    float* zq  = out + (size_t)BATCH * ZDIM;
    float* rec = zq + (size_t)BATCH * EDIM;

    char* ws = (char*)d_ws;
    float* h    = (float*)(ws);                               // 8 MB
    float* h2   = (float*)(ws + 8388608);                     // 8 MB
    unsigned short* hb   = (unsigned short*)(ws + 16777216);  // 4 MB
    unsigned short* w2bt = (unsigned short*)(ws + 20971520);  // 16 MB
    float* w2t  = (float*)(ws + 37748736);                    // 32 MB
    char* tail = ws + 71303168;
    const size_t WS_NEED2 = 71303168 + 1572864 + 256;         // ~72.9 MB
    const bool fast2 = ws_size >= WS_NEED2;
    if (!fast2) tail = ws + 16777216;                         // fallback layout
    int*   tok  = (int*)(tail);
    float* s1v  = (float*)(tail + 524288);
    int*   amb  = (int*)(tail + 1048576);
    int*   cnt  = (int*)(tail + 1572864);

    dim3 blk(256);

    // encoder layer 1 (f32 exact; bf16 copy fused when fast2)
    gemm_f32_64<true ><<<dim3(DMODEL / 64, BATCH / 64), blk, 0, stream>>>(
        x, ew1, eb1, h, fast2 ? hb : (unsigned short*)nullptr,
        BATCH, DMODEL, DMODEL);

    if (fast2) {
        transpose_w2<<<dim3(ZDIM / 32, DMODEL / 32), blk, 0, stream>>>(
            ew2, w2bt, w2t, DMODEL, ZDIM, 1);
        zero_count<<<dim3(1), dim3(64), 0, stream>>>(cnt);
        gemm_mfma_bf16<<<dim3(ZDIM / 128, BATCH / 128), blk, 0, stream>>>(
            hb, w2bt, eb2, z, BATCH, ZDIM, DMODEL);
        sample_tokens_ilp<<<dim3(BATCH * KTOK / 4), blk, 0, stream>>>(
            z, tok, s1v, amb, cnt);
        refine_tokens2<<<dim3(4096), dim3(64), 0, stream>>>(
            z, h, w2t, eb2, amb, cnt, s1v, tok);
    } else {
        gemm_f32<false><<<dim3(ZDIM / 128, BATCH / 128), blk, 0, stream>>>(
            h, ew2, eb2, z, BATCH, ZDIM, DMODEL);
        sample_tokens_simple<<<dim3(BATCH * KTOK / 4), blk, 0, stream>>>(z, tok);
    }

    gather_zq<<<dim3(BATCH), blk, 0, stream>>>(tok, cb, zq);

    // decoder (f32 exact)
    gemm_f32_64<true ><<<dim3(DMODEL / 64, BATCH / 64), blk, 0, stream>>>(
        zq, dw1, db1, h2, nullptr, BATCH, DMODEL, EDIM);
    gemm_f32_64<false><<<dim3(DMODEL / 64, BATCH / 64), blk, 0, stream>>>(
        h2, dw2, db2, rec, nullptr, BATCH, DMODEL, DMODEL);
}

// Round 9
// 395.121 us; speedup vs baseline: 1.3344x; 1.1013x over previous
//
#include <hip/hip_runtime.h>
#include <hip/hip_bf16.h>
#include <math.h>
#include <stdint.h>

// ---------------------------------------------------------------------------
// VectorTokenizer: x ->(enc MLP)-> z -> categorical(threefry key(1)) tokens
//   -> z_q = sum of codebook rows -> (dec MLP) -> rec
// Outputs: z (4096*16384) | z_q (4096*256) | rec (4096*512), f32
//
// R9: (1) MFMA GEMM -> 3-buffer pipeline with counted s_waitcnt vmcnt(8/4/0)
// + raw s_barrier (drain-latency regime at K=512, unlike m139's null regime);
// (2) decoder layers -> bf16 MFMA (z passed with 4.5x margin under identical
// math; z_q/tokens stay exact); (3) sampler max-only + ballot recovery (ties
// are flagged ambiguous -> refine decides, so top-2/tie bookkeeping drops).
// ---------------------------------------------------------------------------

#define BATCH 4096
#define KTOK  32
#define VOCAB 512
#define DMODEL 512
#define ZDIM  16384
#define EDIM  256
#define MARGIN 0.03125f

typedef __attribute__((ext_vector_type(8))) short short8v;
typedef __attribute__((ext_vector_type(4))) float f32x4;

// ----------------------- threefry2x32 (JAX-compatible) ---------------------
__device__ __forceinline__ void threefry2x32(uint32_t k0, uint32_t k1,
                                             uint32_t x0, uint32_t x1,
                                             uint32_t& y0, uint32_t& y1) {
    uint32_t ks0 = k0, ks1 = k1, ks2 = k0 ^ k1 ^ 0x1BD11BDAu;
    x0 += ks0; x1 += ks1;
#define TFR(r) { x0 += x1; x1 = __builtin_rotateleft32(x1, r); x1 ^= x0; }
    TFR(13) TFR(15) TFR(26) TFR(6)
    x0 += ks1; x1 += ks2 + 1u;
    TFR(17) TFR(29) TFR(16) TFR(24)
    x0 += ks2; x1 += ks0 + 2u;
    TFR(13) TFR(15) TFR(26) TFR(6)
    x0 += ks0; x1 += ks1 + 3u;
    TFR(17) TFR(29) TFR(16) TFR(24)
    x0 += ks1; x1 += ks2 + 4u;
    TFR(13) TFR(15) TFR(26) TFR(6)
    x0 += ks2; x1 += ks0 + 5u;
#undef TFR
    y0 = x0; y1 = x1;
}

// 4 consecutive counters, manually interleaved (issue-rate pipelining)
__device__ __forceinline__ void threefry4x(uint32_t e,
                                           uint32_t& o0, uint32_t& o1,
                                           uint32_t& o2, uint32_t& o3) {
    const uint32_t KS2 = 0x1BD11BDBu;
    uint32_t xa = 0u, ya = e + 1u;
    uint32_t xb = 0u, yb = e + 2u;
    uint32_t xc = 0u, yc = e + 3u;
    uint32_t xd = 0u, yd = e + 4u;
#define RR(r) \
    xa += ya; xb += yb; xc += yc; xd += yd; \
    ya = __builtin_rotateleft32(ya, r) ^ xa; \
    yb = __builtin_rotateleft32(yb, r) ^ xb; \
    yc = __builtin_rotateleft32(yc, r) ^ xc; \
    yd = __builtin_rotateleft32(yd, r) ^ xd;
    RR(13) RR(15) RR(26) RR(6)
    xa += 1u; xb += 1u; xc += 1u; xd += 1u;
    ya += KS2 + 1u; yb += KS2 + 1u; yc += KS2 + 1u; yd += KS2 + 1u;
    RR(17) RR(29) RR(16) RR(24)
    xa += KS2; xb += KS2; xc += KS2; xd += KS2;
    ya += 2u; yb += 2u; yc += 2u; yd += 2u;
    RR(13) RR(15) RR(26) RR(6)
    ya += 4u; yb += 4u; yc += 4u; yd += 4u;
    RR(17) RR(29) RR(16) RR(24)
    xa += 1u; xb += 1u; xc += 1u; xd += 1u;
    ya += KS2 + 4u; yb += KS2 + 4u; yc += KS2 + 4u; yd += KS2 + 4u;
    RR(13) RR(15) RR(26) RR(6)
    xa += KS2; xb += KS2; xc += KS2; xd += KS2;
    ya += 5u; yb += 5u; yc += 5u; yd += 5u;
#undef RR
    o0 = xa ^ ya; o1 = xb ^ yb; o2 = xc ^ yc; o3 = xd ^ yd;
}

// exact path (refine): matches JAX bit-for-bit
__device__ __forceinline__ float jax_gumbel(uint64_t e) {
    const float TINY = 1.17549435e-38f;
    uint32_t y0, y1;
    threefry2x32(0u, 1u, (uint32_t)(e >> 32), (uint32_t)(e & 0xffffffffull), y0, y1);
    uint32_t bits = y0 ^ y1;
    float u = __uint_as_float(0x3f800000u | (bits >> 9)) - 1.0f;
    u = u * 1.0f + TINY;
    u = fmaxf(TINY, u);
    return -logf(-logf(u));
}

// fast-filter gumbel: |g_fast - g_exact| <~ 1e-4 << MARGIN
__device__ __forceinline__ float gumbel_from_bits(uint32_t bits) {
    const float TINY = 1.17549435e-38f;
    const float LN2 = 0.69314718056f;
    float f = __uint_as_float(0x3f800000u | (bits >> 9));  // [1,2)
    float u = f - 1.0f;          // exact (Sterbenz)
    float d = 2.0f - f;          // exact = 1-u
    u = fmaxf(u, TINY);
    float e_hw = -LN2 * __builtin_amdgcn_logf(u);
    float e_poly = d * fmaf(d, fmaf(d, 0.33333333f, 0.5f), 1.0f);
    float e = (d < 0.002f) ? e_poly : e_hw;
    return -LN2 * __builtin_amdgcn_logf(e);
}

__device__ __forceinline__ float fast_gumbel(uint32_t e32) {
    uint32_t y0, y1;
    threefry2x32(0u, 1u, 0u, e32, y0, y1);
    return gumbel_from_bits(y0 ^ y1);
}

__device__ __forceinline__ unsigned short f32_to_bf16_rne(float f) {
    uint32_t u = __float_as_uint(f);
    uint32_t r = (u + 0x7fffu + ((u >> 16) & 1u)) >> 16;
    return (unsigned short)r;
}

__device__ __forceinline__ void gload16(const unsigned short* src,
                                        unsigned short* lds_base) {
    __builtin_amdgcn_global_load_lds(
        (const __attribute__((address_space(1))) unsigned int*)src,
        (__attribute__((address_space(3))) unsigned int*)lds_base, 16, 0, 0);
}

// ------------------ tiled f32 GEMM, 64x64 (enc1, exact) --------------------
template<bool RELU>
__global__ __launch_bounds__(256)
void gemm_f32_64(const float* __restrict__ A, const float* __restrict__ B,
                 const float* __restrict__ bias, float* __restrict__ C,
                 unsigned short* __restrict__ Cb,
                 int M, int N, int K) {
    constexpr int BK = 16;
    __shared__ __align__(16) float As[BK][68];
    __shared__ __align__(16) float Bs[BK][68];

    const int tid = threadIdx.x;
    const int tx = tid % 16;
    const int ty = tid / 16;
    const int brow = blockIdx.y * 64;
    const int bcol = blockIdx.x * 64;

    float acc[4][4] = {};

    for (int k0 = 0; k0 < K; k0 += BK) {
        {
            int r = tid >> 2, c4 = tid & 3;
            float4 v = *(const float4*)&A[(size_t)(brow + r) * K + k0 + c4 * 4];
            As[c4 * 4 + 0][r] = v.x;
            As[c4 * 4 + 1][r] = v.y;
            As[c4 * 4 + 2][r] = v.z;
            As[c4 * 4 + 3][r] = v.w;
        }
        {
            int r = tid >> 4, c4 = tid & 15;
            *(float4*)&Bs[r][c4 * 4] = *(const float4*)&B[(size_t)(k0 + r) * N + bcol + c4 * 4];
        }
        __syncthreads();

#pragma unroll
        for (int kk = 0; kk < BK; ++kk) {
            float a[4], b[4];
            *(float4*)&a[0] = *(const float4*)&As[kk][ty * 4];
            *(float4*)&b[0] = *(const float4*)&Bs[kk][tx * 4];
#pragma unroll
            for (int i = 0; i < 4; ++i)
#pragma unroll
                for (int j = 0; j < 4; ++j)
                    acc[i][j] = fmaf(a[i], b[j], acc[i][j]);
        }
        __syncthreads();
    }

#pragma unroll
    for (int i = 0; i < 4; ++i) {
        int row = brow + ty * 4 + i;
        int col = bcol + tx * 4;
        float4 v;
        v.x = acc[i][0] + bias[col + 0];
        v.y = acc[i][1] + bias[col + 1];
        v.z = acc[i][2] + bias[col + 2];
        v.w = acc[i][3] + bias[col + 3];
        if (RELU) {
            v.x = fmaxf(v.x, 0.0f); v.y = fmaxf(v.y, 0.0f);
            v.z = fmaxf(v.z, 0.0f); v.w = fmaxf(v.w, 0.0f);
        }
        *(float4*)&C[(size_t)row * N + col] = v;
        if (Cb) {
            ushort4 o;
            o.x = f32_to_bf16_rne(v.x);
            o.y = f32_to_bf16_rne(v.y);
            o.z = f32_to_bf16_rne(v.z);
            o.w = f32_to_bf16_rne(v.w);
            *(ushort4*)&Cb[(size_t)row * N + col] = o;
        }
    }
}

// ---------------- tiled f32 GEMM, 128x128 (fallback paths) -----------------
template<bool RELU>
__global__ __launch_bounds__(256)
void gemm_f32(const float* __restrict__ A, const float* __restrict__ B,
              const float* __restrict__ bias, float* __restrict__ C,
              int M, int N, int K) {
    constexpr int BM = 128, BN = 128, BK = 16, TM = 8, TN = 8;
    __shared__ __align__(16) float As[BK][BM + 4];
    __shared__ __align__(16) float Bs[BK][BN + 4];

    const int tid = threadIdx.x;
    const int tx = tid % (BN / TN);
    const int ty = tid / (BN / TN);
    const int brow = blockIdx.y * BM;
    const int bcol = blockIdx.x * BN;

    float acc[TM][TN] = {};

    for (int k0 = 0; k0 < K; k0 += BK) {
#pragma unroll
        for (int f = tid; f < BM * BK / 4; f += 256) {
            int r = f / (BK / 4);
            int c4 = f % (BK / 4);
            float4 v = *(const float4*)&A[(size_t)(brow + r) * K + k0 + c4 * 4];
            As[c4 * 4 + 0][r] = v.x;
            As[c4 * 4 + 1][r] = v.y;
            As[c4 * 4 + 2][r] = v.z;
            As[c4 * 4 + 3][r] = v.w;
        }
#pragma unroll
        for (int f = tid; f < BK * BN / 4; f += 256) {
            int r = f / (BN / 4);
            int c4 = f % (BN / 4);
            *(float4*)&Bs[r][c4 * 4] = *(const float4*)&B[(size_t)(k0 + r) * N + bcol + c4 * 4];
        }
        __syncthreads();

#pragma unroll
        for (int kk = 0; kk < BK; ++kk) {
            float a[TM], b[TN];
            *(float4*)&a[0] = *(const float4*)&As[kk][ty * TM];
            *(float4*)&a[4] = *(const float4*)&As[kk][ty * TM + 4];
            *(float4*)&b[0] = *(const float4*)&Bs[kk][tx * TN];
            *(float4*)&b[4] = *(const float4*)&Bs[kk][tx * TN + 4];
#pragma unroll
            for (int i = 0; i < TM; ++i)
#pragma unroll
                for (int j = 0; j < TN; ++j)
                    acc[i][j] = fmaf(a[i], b[j], acc[i][j]);
        }
        __syncthreads();
    }

#pragma unroll
    for (int i = 0; i < TM; ++i) {
        int row = brow + ty * TM + i;
#pragma unroll
        for (int j = 0; j < TN; j += 4) {
            int col = bcol + tx * TN + j;
            float4 v;
            v.x = acc[i][j + 0] + bias[col + 0];
            v.y = acc[i][j + 1] + bias[col + 1];
            v.z = acc[i][j + 2] + bias[col + 2];
            v.w = acc[i][j + 3] + bias[col + 3];
            if (RELU) {
                v.x = fmaxf(v.x, 0.0f); v.y = fmaxf(v.y, 0.0f);
                v.z = fmaxf(v.z, 0.0f); v.w = fmaxf(v.w, 0.0f);
            }
            *(float4*)&C[(size_t)row * N + col] = v;
        }
    }
}

// ---- f32 [R][C] -> bf16 [C][R] transpose (+ optional f32 [C][R]) ----------
__global__ __launch_bounds__(256)
void transpose_w2(const float* __restrict__ src, unsigned short* __restrict__ dstb,
                  float* __restrict__ dstf, int R, int C, int writeF) {
    __shared__ float tile[32][33];
    const int c0 = blockIdx.x * 32, r0 = blockIdx.y * 32;
    const int tx = threadIdx.x % 32, ty = threadIdx.x / 32;
#pragma unroll
    for (int i = ty; i < 32; i += 8)
        tile[i][tx] = src[(size_t)(r0 + i) * C + c0 + tx];
    __syncthreads();
#pragma unroll
    for (int i = ty; i < 32; i += 8) {
        float v = tile[tx][i];
        size_t o = (size_t)(c0 + i) * R + r0 + tx;
        dstb[o] = f32_to_bf16_rne(v);
        if (writeF) dstf[o] = v;
    }
}

// -------- bf16 MFMA GEMM, 3-buffer pipeline w/ counted vmcnt ---------------
// 128x128 tile, BK=32, 4 waves (2x2). Depth-2 prefetch stays in flight
// across raw s_barrier; per-iter waits: vmcnt(8)/(4)/(0) by distance to end.
// L2-aware XCD mapping (xcd owns gridDim.y/8 contiguous by-rows).
template<bool RELU, bool WF32, bool WBF16>
__global__ __launch_bounds__(256)
void gemm_mfma(const unsigned short* __restrict__ A,
               const unsigned short* __restrict__ Bt,
               const float* __restrict__ bias,
               float* __restrict__ C, unsigned short* __restrict__ Cb,
               int M, int N, int K) {
    constexpr int BM = 128, BN = 128, BK = 32;
    constexpr int TSZ = BM * BK;                 // 4096 elems / buffer
    __shared__ unsigned short As[3 * TSZ];
    __shared__ unsigned short Bs[3 * TSZ];

    const int lid = blockIdx.y * gridDim.x + blockIdx.x;
    const int xcd = lid & 7;
    const int kk2 = lid >> 3;
    const int rpx = gridDim.y >> 3;
    const int by = xcd * rpx + (kk2 % rpx);
    const int bx = kk2 / rpx;

    const int tid = threadIdx.x;
    const int wid = tid >> 6;
    const int lane = tid & 63;
    const int wr = wid >> 1, wc = wid & 1;
    const int l15 = lane & 15, lq = lane >> 4;
    const int brow = by * BM;
    const int bcol = bx * BN;

    const int g1 = tid;
    const int g2 = tid + 256;
    const size_t a1 = (size_t)(brow + (g1 >> 2)) * K + (g1 & 3) * 8;
    const size_t a2 = (size_t)(brow + (g2 >> 2)) * K + (g2 & 3) * 8;
    const size_t b1 = (size_t)(bcol + (g1 >> 2)) * K + (g1 & 3) * 8;
    const size_t b2 = (size_t)(bcol + (g2 >> 2)) * K + (g2 & 3) * 8;
    const int off1 = wid * 64 * 8;
    const int off2 = (256 + wid * 64) * 8;

    f32x4 acc[4][4];
#pragma unroll
    for (int m = 0; m < 4; ++m)
#pragma unroll
        for (int n = 0; n < 4; ++n) acc[m][n] = (f32x4){0.f, 0.f, 0.f, 0.f};

    const int NK = K / BK;

#define STAGE(kt, bufi) { \
    const int k0_ = (kt) * BK; \
    const int o_ = (bufi) * TSZ; \
    gload16(A + a1 + k0_, As + o_ + off1); \
    gload16(A + a2 + k0_, As + o_ + off2); \
    gload16(Bt + b1 + k0_, Bs + o_ + off1); \
    gload16(Bt + b2 + k0_, Bs + o_ + off2); }

    // prologue: stage tiles 0 and 1
    STAGE(0, 0)
    if (NK > 1) STAGE(1, 1)

    int buf = 0;
    for (int kt = 0; kt < NK; ++kt) {
        if (kt + 2 < NK) {
            int nb = buf + 2; if (nb >= 3) nb -= 3;
            STAGE(kt + 2, nb)
        }
        // counted wait: leave younger prefetches in flight
        if (kt + 2 < NK)      asm volatile("s_waitcnt vmcnt(8)" ::: "memory");
        else if (kt + 1 < NK) asm volatile("s_waitcnt vmcnt(4)" ::: "memory");
        else                  asm volatile("s_waitcnt vmcnt(0)" ::: "memory");
        __builtin_amdgcn_s_barrier();
        __builtin_amdgcn_sched_barrier(0);

        const int cb = buf * TSZ;
        short8v af[4], bf[4];
#pragma unroll
        for (int m = 0; m < 4; ++m)
            af[m] = *(const short8v*)&As[cb + (wr * 64 + m * 16 + l15) * BK + lq * 8];
#pragma unroll
        for (int n = 0; n < 4; ++n)
            bf[n] = *(const short8v*)&Bs[cb + (wc * 64 + n * 16 + l15) * BK + lq * 8];
#pragma unroll
        for (int m = 0; m < 4; ++m)
#pragma unroll
            for (int n = 0; n < 4; ++n)
                acc[m][n] = __builtin_amdgcn_mfma_f32_16x16x32_bf16(
                    af[m], bf[n], acc[m][n], 0, 0, 0);
        __builtin_amdgcn_s_barrier();   // reading done; next STAGE may overwrite
        ++buf; if (buf == 3) buf = 0;
    }
#undef STAGE

#pragma unroll
    for (int m = 0; m < 4; ++m) {
#pragma unroll
        for (int n = 0; n < 4; ++n) {
            int col = bcol + wc * 64 + n * 16 + l15;
            float bv = bias[col];
#pragma unroll
            for (int r = 0; r < 4; ++r) {
                int row = brow + wr * 64 + m * 16 + lq * 4 + r;
                float v = acc[m][n][r] + bv;
                if (RELU) v = fmaxf(v, 0.0f);
                if (WF32) C[(size_t)row * N + col] = v;
                if (WBF16) Cb[(size_t)row * N + col] = f32_to_bf16_rne(v);
            }
        }
    }
}

// -------- sampler v5: max-only + ballot recovery (1 wave / token) ----------
// Ties are flagged ambiguous (count>=2) and resolved exactly by refine, so
// no tie-break or top-2 bookkeeping is needed here.
__global__ __launch_bounds__(256)
void sample_tokens_max(const float* __restrict__ z, int* __restrict__ tokens,
                       float* __restrict__ s1v, int* __restrict__ amb,
                       int* __restrict__ ambCount) {
    const int wave = threadIdx.x >> 6;
    const int lane = threadIdx.x & 63;
    const uint32_t t = blockIdx.x * 4 + wave;
    const float* zr = z + (size_t)t * VOCAB;

    float sc[8];
    float m = -INFINITY;
#pragma unroll
    for (int half = 0; half < 2; ++half) {
        const int e0 = half * 256 + lane * 4;
        const float4 zv = *(const float4*)&zr[e0];
        uint32_t b0, b1, b2, b3;
        threefry4x(t * (uint32_t)VOCAB + (uint32_t)e0, b0, b1, b2, b3);
        sc[half * 4 + 0] = zv.x + gumbel_from_bits(b0);
        sc[half * 4 + 1] = zv.y + gumbel_from_bits(b1);
        sc[half * 4 + 2] = zv.z + gumbel_from_bits(b2);
        sc[half * 4 + 3] = zv.w + gumbel_from_bits(b3);
        m = fmaxf(m, fmaxf(fmaxf(sc[half * 4 + 0], sc[half * 4 + 1]),
                           fmaxf(sc[half * 4 + 2], sc[half * 4 + 3])));
    }
#pragma unroll
    for (int off = 32; off > 0; off >>= 1)
        m = fmaxf(m, __shfl_xor(m, off));

    const float thr = m - MARGIN;
    int nge = 0;
    int vsel = VOCAB;
#pragma unroll
    for (int idx = 0; idx < 8; ++idx) {
        unsigned long long mge = __ballot(sc[idx] >= thr);
        nge += __popcll(mge);
        unsigned long long meq = __ballot(sc[idx] == m);
        if (vsel == VOCAB && meq) {
            int ln = __builtin_ctzll(meq);
            vsel = (idx >> 2) * 256 + ln * 4 + (idx & 3);
        }
    }
    if (lane == 0) {
        tokens[t] = vsel;
        s1v[t] = m;
        if (nge >= 2) {
            int idx = atomicAdd(ambCount, 1);
            amb[idx] = (int)t;
        }
    }
}

// ------ refine: w2t f32 rows, ballot-compacted candidates ------------------
__global__ __launch_bounds__(64)
void refine_tokens2(const float* __restrict__ z, const float* __restrict__ h,
                    const float* __restrict__ w2t, const float* __restrict__ eb2,
                    const int* __restrict__ amb, const int* __restrict__ ambCount,
                    const float* __restrict__ s1v, int* __restrict__ tok) {
    __shared__ float hrow[DMODEL];
    __shared__ int candv[64];
    const int cnt = *ambCount;
    const int lane = threadIdx.x;

    for (int i = blockIdx.x; i < cnt; i += gridDim.x) {
        const int t = amb[i];
        const int b = t >> 5;
        const int kb = t & 31;
        const float* zr = z + (size_t)t * VOCAB;
        const float s1 = s1v[t];

        {
            float4 hv0 = *(const float4*)&h[(size_t)b * DMODEL + lane * 8];
            float4 hv1 = *(const float4*)&h[(size_t)b * DMODEL + lane * 8 + 4];
            *(float4*)&hrow[lane * 8] = hv0;
            *(float4*)&hrow[lane * 8 + 4] = hv1;
        }

        int base = 0;
#pragma unroll
        for (int half = 0; half < 2; ++half) {
            int e0 = half * 256 + lane * 4;
            float4 zv = *(const float4*)&zr[e0];
            float zs[4] = {zv.x, zv.y, zv.z, zv.w};
#pragma unroll
            for (int j = 0; j < 4; ++j) {
                int v = e0 + j;
                float s = zs[j] + fast_gumbel((uint32_t)t * VOCAB + v);
                bool pred = (s >= s1 - MARGIN);
                unsigned long long mask = __ballot(pred);
                if (pred) {
                    int slot = base + __popcll(mask & ((1ull << lane) - 1ull));
                    if (slot < 64) candv[slot] = v;
                }
                base += __popcll(mask);
            }
        }
        __syncthreads();
        const int ncand = base < 64 ? base : 64;

        float bestE = -INFINITY;
        int bestV = VOCAB;
        if (lane < ncand) {
            const int v = candv[lane];
            const int n = kb * VOCAB + v;
            const float* wr_ = w2t + (size_t)n * DMODEL;
            float acc = 0.f;
#pragma unroll 8
            for (int k = 0; k < DMODEL; ++k)
                acc = fmaf(hrow[k], wr_[k], acc);
            bestE = acc + eb2[n] + jax_gumbel((uint64_t)t * VOCAB + v);
            bestV = v;
        }
#pragma unroll
        for (int off = 32; off > 0; off >>= 1) {
            float oe = __shfl_down(bestE, off);
            int ov = __shfl_down(bestV, off);
            if (oe > bestE || (oe == bestE && ov < bestV)) { bestE = oe; bestV = ov; }
        }
        if (lane == 0) tok[t] = bestV;
        __syncthreads();
    }
}

// ----------------- simple sampler (ws-too-small fallback) ------------------
__global__ __launch_bounds__(256)
void sample_tokens_simple(const float* __restrict__ z, int* __restrict__ tokens) {
    const int wave = threadIdx.x >> 6;
    const int lane = threadIdx.x & 63;
    const size_t t = (size_t)blockIdx.x * 4 + wave;
    const float* zr = z + t * VOCAB;
    float zv[8];
    *(float4*)&zv[0] = *(const float4*)&zr[lane * 8];
    *(float4*)&zv[4] = *(const float4*)&zr[lane * 8 + 4];
    const uint64_t ebase = t * (uint64_t)VOCAB + (uint64_t)lane * 8;
    float best = -INFINITY;
    int bestv = 0;
#pragma unroll
    for (int j = 0; j < 8; ++j) {
        float g = jax_gumbel(ebase + j);
        float s = zv[j] + g;
        int v = lane * 8 + j;
        if (s > best || (s == best && v < bestv)) { best = s; bestv = v; }
    }
#pragma unroll
    for (int off = 32; off > 0; off >>= 1) {
        float ob = __shfl_down(best, off);
        int ov = __shfl_down(bestv, off);
        if (ob > best || (ob == best && ov < bestv)) { best = ob; bestv = ov; }
    }
    if (lane == 0) tokens[t] = bestv;
}

__global__ __launch_bounds__(64)
void zero_count(int* p) { if (threadIdx.x == 0) *p = 0; }

// ---------------- z_q gather (exact f32 + optional bf16 copy) --------------
__global__ __launch_bounds__(256)
void gather_zq(const int* __restrict__ tokens, const float* __restrict__ codebook,
               float* __restrict__ zq, unsigned short* __restrict__ zqb) {
    const int b = blockIdx.x;
    const int d = threadIdx.x;
    float s = 0.0f;
#pragma unroll
    for (int k = 0; k < KTOK; ++k) {
        int tok = tokens[b * KTOK + k];
        s += codebook[(size_t)(k * VOCAB + tok) * EDIM + d];
    }
    zq[(size_t)b * EDIM + d] = s;
    if (zqb) zqb[(size_t)b * EDIM + d] = f32_to_bf16_rne(s);
}

// ------------------------------- launcher ----------------------------------
extern "C" void kernel_launch(void* const* d_in, const int* in_sizes, int n_in,
                              void* d_out, int out_size, void* d_ws, size_t ws_size,
                              hipStream_t stream) {
    const float* x   = (const float*)d_in[0];
    const float* ew1 = (const float*)d_in[1];
    const float* eb1 = (const float*)d_in[2];
    const float* ew2 = (const float*)d_in[3];
    const float* eb2 = (const float*)d_in[4];
    const float* cb  = (const float*)d_in[5];
    const float* dw1 = (const float*)d_in[6];
    const float* db1 = (const float*)d_in[7];
    const float* dw2 = (const float*)d_in[8];
    const float* db2 = (const float*)d_in[9];

    float* out = (float*)d_out;
    float* z   = out;
    float* zq  = out + (size_t)BATCH * ZDIM;
    float* rec = zq + (size_t)BATCH * EDIM;

    char* ws = (char*)d_ws;
    float* h    = (float*)(ws);                               // 8 MB
    // repurposed 8MB..16MB region (h2 no longer needed in f32):
    unsigned short* zqb   = (unsigned short*)(ws + 8388608);  // 2 MB
    unsigned short* h2b   = (unsigned short*)(ws + 10485760); // 4 MB
    unsigned short* dw1tb = (unsigned short*)(ws + 14680064); // 256 KB
    unsigned short* dw2tb = (unsigned short*)(ws + 14942208); // 512 KB
    float* h2f  = (float*)(ws + 8388608);                     // fallback f32 h2
    unsigned short* hb   = (unsigned short*)(ws + 16777216);  // 4 MB
    unsigned short* w2bt = (unsigned short*)(ws + 20971520);  // 16 MB
    float* w2t  = (float*)(ws + 37748736);                    // 32 MB
    char* tail = ws + 71303168;
    const size_t WS_NEED2 = 71303168 + 1572864 + 256;         // ~72.9 MB
    const bool fast2 = ws_size >= WS_NEED2;
    if (!fast2) tail = ws + 16777216;
    int*   tok  = (int*)(tail);
    float* s1v  = (float*)(tail + 524288);
    int*   amb  = (int*)(tail + 1048576);
    int*   cnt  = (int*)(tail + 1572864);

    dim3 blk(256);

    // encoder layer 1 (f32 exact; bf16 copy fused when fast2)
    gemm_f32_64<true ><<<dim3(DMODEL / 64, BATCH / 64), blk, 0, stream>>>(
        x, ew1, eb1, h, fast2 ? hb : (unsigned short*)nullptr,
        BATCH, DMODEL, DMODEL);

    if (fast2) {
        transpose_w2<<<dim3(ZDIM / 32, DMODEL / 32), blk, 0, stream>>>(
            ew2, w2bt, w2t, DMODEL, ZDIM, 1);
        transpose_w2<<<dim3(DMODEL / 32, EDIM / 32), blk, 0, stream>>>(
            dw1, dw1tb, nullptr, EDIM, DMODEL, 0);
        transpose_w2<<<dim3(DMODEL / 32, DMODEL / 32), blk, 0, stream>>>(
            dw2, dw2tb, nullptr, DMODEL, DMODEL, 0);
        zero_count<<<dim3(1), dim3(64), 0, stream>>>(cnt);
        // big GEMM -> z
        gemm_mfma<false, true, false><<<dim3(ZDIM / 128, BATCH / 128), blk, 0, stream>>>(
            hb, w2bt, eb2, z, nullptr, BATCH, ZDIM, DMODEL);
        sample_tokens_max<<<dim3(BATCH * KTOK / 4), blk, 0, stream>>>(
            z, tok, s1v, amb, cnt);
        refine_tokens2<<<dim3(4096), dim3(64), 0, stream>>>(
            z, h, w2t, eb2, amb, cnt, s1v, tok);
        gather_zq<<<dim3(BATCH), blk, 0, stream>>>(tok, cb, zq, zqb);
        // decoder via bf16 MFMA (rec threshold scales with max|rec|; same
        // relative margin as z which passed at 4.5x)
        gemm_mfma<true, false, true><<<dim3(DMODEL / 128, BATCH / 128), blk, 0, stream>>>(
            zqb, dw1tb, db1, nullptr, h2b, BATCH, DMODEL, EDIM);
        gemm_mfma<false, true, false><<<dim3(DMODEL / 128, BATCH / 128), blk, 0, stream>>>(
            h2b, dw2tb, db2, rec, nullptr, BATCH, DMODEL, DMODEL);
    } else {
        gemm_f32<false><<<dim3(ZDIM / 128, BATCH / 128), blk, 0, stream>>>(
            h, ew2, eb2, z, BATCH, ZDIM, DMODEL);
        sample_tokens_simple<<<dim3(BATCH * KTOK / 4), blk, 0, stream>>>(z, tok);
        gather_zq<<<dim3(BATCH), blk, 0, stream>>>(tok, cb, zq, nullptr);
        gemm_f32_64<true ><<<dim3(DMODEL / 64, BATCH / 64), blk, 0, stream>>>(
            zq, dw1, db1, h2f, nullptr, BATCH, DMODEL, EDIM);
        gemm_f32_64<false><<<dim3(DMODEL / 64, BATCH / 64), blk, 0, stream>>>(
            h2f, dw2, db2, rec, nullptr, BATCH, DMODEL, DMODEL);
    }
}